// Round 8
// baseline (755.633 us; speedup 1.0000x reference)
//
#include <hip/hip_runtime.h>
#include <cstdint>
#include <cstddef>

#define N_NODES_C 200000
#define N_EDGES_C 600000
#define NUM_GRAPHS_C 20000

constexpr float NEG_SLOPE = 0.2f;
constexpr float LN_EPS = 1e-5f;

// ---------------- CSR build ----------------

__global__ __launch_bounds__(256) void count_deg_kernel(const int* __restrict__ dst,
                                                        int* __restrict__ deg, int E) {
  int e = blockIdx.x * 256 + threadIdx.x;
  if (e < E) atomicAdd(&deg[dst[e]], 1);
}

// exclusive scan, 1024 elements per block (256 threads x 4)
__global__ __launch_bounds__(256) void scan_kernel(const int* __restrict__ in,
                                                   int* __restrict__ out,
                                                   int* __restrict__ bsums, int n) {
  __shared__ int ss[256];
  int t = threadIdx.x;
  int base = blockIdx.x * 1024 + t * 4;
  int v[4];
  int s = 0;
#pragma unroll
  for (int j = 0; j < 4; ++j) {
    v[j] = (base + j < n) ? in[base + j] : 0;
    s += v[j];
  }
  ss[t] = s;
  __syncthreads();
  for (int off = 1; off < 256; off <<= 1) {
    int x = (t >= off) ? ss[t - off] : 0;
    __syncthreads();
    ss[t] += x;
    __syncthreads();
  }
  int incl = ss[t];
  int excl = incl - s;
  if (bsums != nullptr && t == 255) bsums[blockIdx.x] = incl;
  int run = excl;
#pragma unroll
  for (int j = 0; j < 4; ++j) {
    if (base + j < n) out[base + j] = run;
    run += v[j];
  }
}

__global__ __launch_bounds__(256) void scan_addoff_kernel(int* __restrict__ data,
                                                          const int* __restrict__ boff,
                                                          int n, int total) {
  int base = blockIdx.x * 1024 + threadIdx.x * 4;
  int add = boff[blockIdx.x];
#pragma unroll
  for (int j = 0; j < 4; ++j) {
    if (base + j < n) data[base + j] += add;
  }
  if (blockIdx.x == 0 && threadIdx.x == 0) data[n] = total;
}

__global__ __launch_bounds__(256) void fill_csr_kernel(const int* __restrict__ src,
                                                       const int* __restrict__ dst,
                                                       const int* __restrict__ row_ptr,
                                                       int* __restrict__ cursor,
                                                       int* __restrict__ col, int E) {
  int e = blockIdx.x * 256 + threadIdx.x;
  if (e < E) {
    int d = dst[e];
    int p = atomicAdd(&cursor[d], 1);
    col[row_ptr[d] + p] = src[e];
  }
}

// ---------------- GEMM + att-score epilogue ----------------
// C[M,128] = A[M,128] @ W[128,128]; also asrc/adst from acc registers.
// 32x128 block tile, 4 rows x 4 cols/thread, outer K loop pinned (no spill).

template <int H>
__global__ __launch_bounds__(256) void gemm_att(const float* __restrict__ A,
                                                const float* __restrict__ W,
                                                const float* __restrict__ att_src,
                                                const float* __restrict__ att_dst,
                                                float* __restrict__ C,
                                                float* __restrict__ asrc,
                                                float* __restrict__ adst, int M) {
  __shared__ float As[32][32];
  __shared__ float Ws[32][128];
  int tid = threadIdx.x;
  int tx = tid & 31;   // col group (4 cols)
  int ty = tid >> 5;   // 0..7
  int row0 = blockIdx.x * 32;
  float4 acc[4];
#pragma unroll
  for (int r = 0; r < 4; ++r) acc[r] = make_float4(0.f, 0.f, 0.f, 0.f);

#pragma unroll 1
  for (int k0 = 0; k0 < 128; k0 += 32) {
    {
      int r = tid >> 3;
      int c4 = tid & 7;
      int gr = row0 + r;
      float4 v = make_float4(0.f, 0.f, 0.f, 0.f);
      if (gr < M) v = *(const float4*)(A + (size_t)gr * 128 + k0 + c4 * 4);
      *(float4*)&As[r][c4 * 4] = v;
    }
#pragma unroll
    for (int i = 0; i < 4; ++i) {
      int idx = tid + i * 256;
      int r = idx >> 5;
      int c4 = idx & 31;
      *(float4*)&Ws[r][c4 * 4] = *(const float4*)(W + (size_t)(k0 + r) * 128 + c4 * 4);
    }
    __syncthreads();
#pragma unroll
    for (int kk = 0; kk < 32; ++kk) {
      float4 w = *(const float4*)&Ws[kk][tx * 4];
#pragma unroll
      for (int r = 0; r < 4; ++r) {
        float a = As[ty + r * 8][kk];
        acc[r].x = fmaf(a, w.x, acc[r].x);
        acc[r].y = fmaf(a, w.y, acc[r].y);
        acc[r].z = fmaf(a, w.z, acc[r].z);
        acc[r].w = fmaf(a, w.w, acc[r].w);
      }
    }
    __syncthreads();
  }

  float4 vs = *(const float4*)(att_src + tx * 4);
  float4 vd = *(const float4*)(att_dst + tx * 4);
  constexpr int GRP = 32 / H;  // lanes per head within the 32-col group
#pragma unroll
  for (int r = 0; r < 4; ++r) {
    int gr = row0 + ty + r * 8;
    if (gr < M) *(float4*)(C + (size_t)gr * 128 + tx * 4) = acc[r];
    float ps = acc[r].x * vs.x + acc[r].y * vs.y + acc[r].z * vs.z + acc[r].w * vs.w;
    float pd = acc[r].x * vd.x + acc[r].y * vd.y + acc[r].z * vd.z + acc[r].w * vd.w;
#pragma unroll
    for (int off = 1; off < GRP; off <<= 1) {
      ps += __shfl_xor(ps, off, 64);
      pd += __shfl_xor(pd, off, 64);
    }
    if ((tx & (GRP - 1)) == 0 && gr < M) {
      int hd = tx / GRP;
      asrc[(size_t)gr * H + hd] = ps;
      adst[(size_t)gr * H + hd] = pd;
    }
  }
}

// ---------------- Pass A: edge-parallel denominator accumulation ------------
// No max-shift: scores here are O(+-5) (dots of ~unit vectors with 1/sqrt(d)-
// scaled weights), exp is safe in fp32 and e/sum(e) is mathematically
// identical to the max-shifted reference. denom (<=3.2MB) is L2-resident.
// NOTE: no ev array is stored -> no edge-id/CSR-slot index mismatch possible
// (round-7 bug: ev written by edge id, read by CSR slot).

template <int H>
__global__ __launch_bounds__(256) void edge_denom_kernel(
    const int* __restrict__ src, const int* __restrict__ dst,
    const float* __restrict__ asrc, const float* __restrict__ adst,
    float* __restrict__ denom, int E) {
  int e = blockIdx.x * 256 + threadIdx.x;
  if (e >= E) return;
  int s = src[e], d = dst[e];
  if constexpr (H == 4) {
    float4 a = *(const float4*)(asrc + (size_t)s * 4);
    float4 b = *(const float4*)(adst + (size_t)d * 4);
    float v[4] = {a.x + b.x, a.y + b.y, a.z + b.z, a.w + b.w};
#pragma unroll
    for (int k = 0; k < 4; ++k) {
      float x = v[k];
      x = (x > 0.f) ? x : NEG_SLOPE * x;
      atomicAdd(&denom[(size_t)d * 4 + k], __expf(x));
    }
  } else {
    float x = asrc[s] + adst[d];
    x = (x > 0.f) ? x : NEG_SLOPE * x;
    atomicAdd(&denom[d], __expf(x));
  }
}

// ---------------- Pass B: wave per node, gather + recompute exp -------------
// No shfl, no reductions. Chain: row_ptr -> col -> {asrc gather, h gather}
// -> exp -> fma; 4 edges in flight per iteration. Pad lanes get weight 0.

template <int H, bool RELU, bool LNPOOL>
__global__ __launch_bounds__(256) void gat_agg2_kernel(
    const float* __restrict__ h, const float* __restrict__ asrc,
    const float* __restrict__ adst, const float* __restrict__ denom,
    const int* __restrict__ row_ptr, const int* __restrict__ col,
    const float* __restrict__ bias, const float* __restrict__ gamma,
    const float* __restrict__ beta, const int* __restrict__ batch,
    float* __restrict__ out, float* __restrict__ cnt, int n) {
  int node = (blockIdx.x * 256 + threadIdx.x) >> 6;
  int lane = threadIdx.x & 63;
  if (node >= n) return;
  int e0 = row_ptr[node];
  int ned = row_ptr[node + 1] - e0;  // real edges (self loop handled inline)

  int c0 = lane * 2;
  const int hd = (H == 1) ? 0 : (lane >> 4);  // 32 channels per head

  // my head's adst, self-loop exp, total denominator
  float adH = (H == 4) ? adst[(size_t)node * 4 + hd] : adst[node];
  float selfe;
  {
    float as_ = (H == 4) ? asrc[(size_t)node * 4 + hd] : asrc[node];
    float x = as_ + adH;
    x = (x > 0.f) ? x : NEG_SLOPE * x;
    selfe = __expf(x);
  }
  float dd = ((H == 4) ? denom[(size_t)node * 4 + hd] : denom[node]) + selfe;
  float inv_dd = 1.f / dd;

  // self contribution
  float2 acc;
  {
    float2 hv = *(const float2*)(h + (size_t)node * 128 + c0);
    acc.x = hv.x * selfe;
    acc.y = hv.y * selfe;
  }

  // edge loop, 4-wide: 4 col loads -> 4 asrc gathers + 4 h-row gathers in
  // flight -> 4 exps -> accumulate. Invalid slots get weight 0 (safe addr).
#pragma unroll 1
  for (int t = 0; t < ned; t += 4) {
    int s4[4];
    bool v4[4];
#pragma unroll
    for (int i = 0; i < 4; ++i) {
      int e = t + i;
      v4[i] = e < ned;  // wave-uniform
      s4[i] = v4[i] ? col[e0 + e] : node;
    }
    float a4[4];
    float2 hv4[4];
#pragma unroll
    for (int i = 0; i < 4; ++i) {
      a4[i] = (H == 4) ? asrc[(size_t)s4[i] * 4 + hd] : asrc[s4[i]];
      hv4[i] = *(const float2*)(h + (size_t)s4[i] * 128 + c0);
    }
#pragma unroll
    for (int i = 0; i < 4; ++i) {
      float x = a4[i] + adH;
      x = (x > 0.f) ? x : NEG_SLOPE * x;
      float ee = v4[i] ? __expf(x) : 0.f;
      acc.x = fmaf(hv4[i].x, ee, acc.x);
      acc.y = fmaf(hv4[i].y, ee, acc.y);
    }
  }

  acc.x = fmaf(acc.x, inv_dd, bias[c0]);
  acc.y = fmaf(acc.y, inv_dd, bias[c0 + 1]);
  if (RELU) {
    acc.x = fmaxf(acc.x, 0.f);
    acc.y = fmaxf(acc.y, 0.f);
  }
  if (!LNPOOL) {
    *(float2*)(out + (size_t)node * 128 + c0) = acc;
  } else {
    // LayerNorm across 128 channels held by the wave (2/lane)
    float ssum = acc.x + acc.y;
#pragma unroll
    for (int off = 1; off < 64; off <<= 1) ssum += __shfl_xor(ssum, off, 64);
    float mu = ssum * (1.f / 128.f);
    float dx = acc.x - mu, dy = acc.y - mu;
    float vs2 = dx * dx + dy * dy;
#pragma unroll
    for (int off = 1; off < 64; off <<= 1) vs2 += __shfl_xor(vs2, off, 64);
    float inv = rsqrtf(vs2 * (1.f / 128.f) + LN_EPS);
    float ox = dx * inv * gamma[c0] + beta[c0];
    float oy = dy * inv * gamma[c0 + 1] + beta[c0 + 1];
    int g = batch[node];
    atomicAdd(&out[(size_t)g * 128 + c0], ox);
    atomicAdd(&out[(size_t)g * 128 + c0 + 1], oy);
    if (lane == 0) atomicAdd(&cnt[g], 1.0f);
  }
}

__global__ __launch_bounds__(256) void pool_div_kernel(float* __restrict__ out,
                                                       const float* __restrict__ cnt,
                                                       int total) {
  int i = blockIdx.x * 256 + threadIdx.x;
  if (i < total) out[i] = out[i] / fmaxf(cnt[i >> 7], 1.0f);
}

// ---------------- launch ----------------

extern "C" void kernel_launch(void* const* d_in, const int* in_sizes, int n_in,
                              void* d_out, int out_size, void* d_ws, size_t ws_size,
                              hipStream_t stream) {
  const float* x = (const float*)d_in[0];
  const int* ei = (const int*)d_in[1];
  const int* batch = (const int*)d_in[2];
  const float* W1 = (const float*)d_in[3];
  const float* att_src1 = (const float*)d_in[4];
  const float* att_dst1 = (const float*)d_in[5];
  const float* b1 = (const float*)d_in[6];
  const float* W2 = (const float*)d_in[7];
  const float* att_src2 = (const float*)d_in[8];
  const float* att_dst2 = (const float*)d_in[9];
  const float* b2 = (const float*)d_in[10];
  const float* gamma = (const float*)d_in[11];
  const float* beta = (const float*)d_in[12];
  float* out = (float*)d_out;

  const int N = N_NODES_C, E = N_EDGES_C, G = NUM_GRAPHS_C;
  const int* src = ei;
  const int* dst = ei + E;

  float* p = (float*)d_ws;
  float* h_a = p;   p += (size_t)N * 128;   // h1_pre, later h2_pre
  float* h_b = p;   p += (size_t)N * 128;   // h1 (post relu)
  float* asrc1 = p; p += (size_t)N * 4;
  float* adst1 = p; p += (size_t)N * 4;
  float* asrc2 = p; p += N;
  float* adst2 = p; p += N;
  float* den1 = p;  p += (size_t)N * 4;
  float* den2 = p;  p += N;
  float* cnt = p;   p += G;
  int* ip = (int*)p;
  int* deg = ip;     ip += N;
  int* cursor = ip;  ip += N;
  int* col = ip;     ip += E;
  int* bsums = ip;   ip += 256;
  int* bsums2 = ip;  ip += 256;
  int* row_ptr = ip; ip += N + 1;
  (void)ws_size; (void)in_sizes; (void)n_in; (void)out_size;

  hipMemsetAsync(deg, 0, sizeof(int) * (size_t)N, stream);
  hipMemsetAsync(cursor, 0, sizeof(int) * (size_t)N, stream);
  hipMemsetAsync(cnt, 0, sizeof(float) * (size_t)G, stream);
  hipMemsetAsync(den1, 0, sizeof(float) * (size_t)N * 4, stream);
  hipMemsetAsync(den2, 0, sizeof(float) * (size_t)N, stream);
  hipMemsetAsync(d_out, 0, sizeof(float) * (size_t)G * 128, stream);

  // CSR by destination
  count_deg_kernel<<<(E + 255) / 256, 256, 0, stream>>>(dst, deg, E);
  int nblk = (N + 1023) / 1024;
  scan_kernel<<<nblk, 256, 0, stream>>>(deg, row_ptr, bsums, N);
  scan_kernel<<<1, 256, 0, stream>>>(bsums, bsums2, nullptr, nblk);
  scan_addoff_kernel<<<nblk, 256, 0, stream>>>(row_ptr, bsums2, N, E);
  fill_csr_kernel<<<(E + 255) / 256, 256, 0, stream>>>(src, dst, row_ptr, cursor, col, E);

  int wblocks = (int)(((size_t)N * 64 + 255) / 256);  // wave per node
  int eblocks = (E + 255) / 256;

  // Layer 1: GAT(128 -> 4x32), ReLU
  gemm_att<4><<<(N + 31) / 32, 256, 0, stream>>>(x, W1, att_src1, att_dst1, h_a, asrc1, adst1, N);
  edge_denom_kernel<4><<<eblocks, 256, 0, stream>>>(src, dst, asrc1, adst1, den1, E);
  gat_agg2_kernel<4, true, false><<<wblocks, 256, 0, stream>>>(
      h_a, asrc1, adst1, den1, row_ptr, col, b1, nullptr, nullptr, nullptr, h_b,
      nullptr, N);

  // Layer 2: GAT(128 -> 1x128) + LayerNorm + mean-pool (fused into epilogue)
  gemm_att<1><<<(N + 31) / 32, 256, 0, stream>>>(h_b, W2, att_src2, att_dst2, h_a, asrc2, adst2, N);
  edge_denom_kernel<1><<<eblocks, 256, 0, stream>>>(src, dst, asrc2, adst2, den2, E);
  gat_agg2_kernel<1, false, true><<<wblocks, 256, 0, stream>>>(
      h_a, asrc2, adst2, den2, row_ptr, col, b2, gamma, beta, batch, out, cnt, N);

  pool_div_kernel<<<(G * 128 + 255) / 256, 256, 0, stream>>>(out, cnt, G * 128);
}

// Round 9
// 724.330 us; speedup vs baseline: 1.0432x; 1.0432x over previous
//
#include <hip/hip_runtime.h>
#include <cstdint>
#include <cstddef>

#define N_NODES_C 200000
#define N_EDGES_C 600000
#define NUM_GRAPHS_C 20000

constexpr float NEG_SLOPE = 0.2f;
constexpr float LN_EPS = 1e-5f;

// bf16 helpers (RNE)
static __device__ __forceinline__ unsigned short f2bf(float f) {
  unsigned u = __float_as_uint(f);
  u = (u + 0x7fffu + ((u >> 16) & 1u)) >> 16;
  return (unsigned short)u;
}
static __device__ __forceinline__ float bf2f(unsigned short s) {
  return __uint_as_float(((unsigned)s) << 16);
}

// ---------------- CSR build ----------------

__global__ __launch_bounds__(256) void count_deg_kernel(const int* __restrict__ dst,
                                                        int* __restrict__ deg, int E) {
  int e = blockIdx.x * 256 + threadIdx.x;
  if (e < E) atomicAdd(&deg[dst[e]], 1);
}

// exclusive scan, 1024 elements per block (256 threads x 4)
__global__ __launch_bounds__(256) void scan_kernel(const int* __restrict__ in,
                                                   int* __restrict__ out,
                                                   int* __restrict__ bsums, int n) {
  __shared__ int ss[256];
  int t = threadIdx.x;
  int base = blockIdx.x * 1024 + t * 4;
  int v[4];
  int s = 0;
#pragma unroll
  for (int j = 0; j < 4; ++j) {
    v[j] = (base + j < n) ? in[base + j] : 0;
    s += v[j];
  }
  ss[t] = s;
  __syncthreads();
  for (int off = 1; off < 256; off <<= 1) {
    int x = (t >= off) ? ss[t - off] : 0;
    __syncthreads();
    ss[t] += x;
    __syncthreads();
  }
  int incl = ss[t];
  int excl = incl - s;
  if (bsums != nullptr && t == 255) bsums[blockIdx.x] = incl;
  int run = excl;
#pragma unroll
  for (int j = 0; j < 4; ++j) {
    if (base + j < n) out[base + j] = run;
    run += v[j];
  }
}

__global__ __launch_bounds__(256) void scan_addoff_kernel(int* __restrict__ data,
                                                          const int* __restrict__ boff,
                                                          int n, int total) {
  int base = blockIdx.x * 1024 + threadIdx.x * 4;
  int add = boff[blockIdx.x];
#pragma unroll
  for (int j = 0; j < 4; ++j) {
    if (base + j < n) data[base + j] += add;
  }
  if (blockIdx.x == 0 && threadIdx.x == 0) data[n] = total;
}

__global__ __launch_bounds__(256) void fill_csr_kernel(const int* __restrict__ src,
                                                       const int* __restrict__ dst,
                                                       const int* __restrict__ row_ptr,
                                                       int* __restrict__ cursor,
                                                       int* __restrict__ col, int E) {
  int e = blockIdx.x * 256 + threadIdx.x;
  if (e < E) {
    int d = dst[e];
    int p = atomicAdd(&cursor[d], 1);
    col[row_ptr[d] + p] = src[e];
  }
}

// ---------------- GEMM + att-score epilogue ----------------
// C[M,128] = A[M,128] @ W[128,128]; C written as bf16 (gather/table dtype);
// asrc/adst computed fp32 from the fp32 accumulators. A is fp32 (layer 1)
// or bf16 (layer 2, converted to fp32 while staging into LDS).
// 32x128 block tile, 4 rows x 4 cols/thread, outer K loop pinned (no spill).

template <int H, bool A_BF16>
__global__ __launch_bounds__(256) void gemm_att(const void* __restrict__ Av,
                                                const float* __restrict__ W,
                                                const float* __restrict__ att_src,
                                                const float* __restrict__ att_dst,
                                                unsigned short* __restrict__ Cbf,
                                                float* __restrict__ asrc,
                                                float* __restrict__ adst, int M) {
  __shared__ float As[32][32];
  __shared__ float Ws[32][128];
  int tid = threadIdx.x;
  int tx = tid & 31;   // col group (4 cols)
  int ty = tid >> 5;   // 0..7
  int row0 = blockIdx.x * 32;
  float4 acc[4];
#pragma unroll
  for (int r = 0; r < 4; ++r) acc[r] = make_float4(0.f, 0.f, 0.f, 0.f);

#pragma unroll 1
  for (int k0 = 0; k0 < 128; k0 += 32) {
    {
      int r = tid >> 3;
      int c4 = tid & 7;
      int gr = row0 + r;
      if constexpr (A_BF16) {
        const unsigned short* A = (const unsigned short*)Av;
        ushort4 v = make_ushort4(0, 0, 0, 0);
        if (gr < M) v = *(const ushort4*)(A + (size_t)gr * 128 + k0 + c4 * 4);
        As[r][c4 * 4 + 0] = bf2f(v.x);
        As[r][c4 * 4 + 1] = bf2f(v.y);
        As[r][c4 * 4 + 2] = bf2f(v.z);
        As[r][c4 * 4 + 3] = bf2f(v.w);
      } else {
        const float* A = (const float*)Av;
        float4 v = make_float4(0.f, 0.f, 0.f, 0.f);
        if (gr < M) v = *(const float4*)(A + (size_t)gr * 128 + k0 + c4 * 4);
        *(float4*)&As[r][c4 * 4] = v;
      }
    }
#pragma unroll
    for (int i = 0; i < 4; ++i) {
      int idx = tid + i * 256;
      int r = idx >> 5;
      int c4 = idx & 31;
      *(float4*)&Ws[r][c4 * 4] = *(const float4*)(W + (size_t)(k0 + r) * 128 + c4 * 4);
    }
    __syncthreads();
#pragma unroll
    for (int kk = 0; kk < 32; ++kk) {
      float4 w = *(const float4*)&Ws[kk][tx * 4];
#pragma unroll
      for (int r = 0; r < 4; ++r) {
        float a = As[ty + r * 8][kk];
        acc[r].x = fmaf(a, w.x, acc[r].x);
        acc[r].y = fmaf(a, w.y, acc[r].y);
        acc[r].z = fmaf(a, w.z, acc[r].z);
        acc[r].w = fmaf(a, w.w, acc[r].w);
      }
    }
    __syncthreads();
  }

  float4 vs = *(const float4*)(att_src + tx * 4);
  float4 vd = *(const float4*)(att_dst + tx * 4);
  constexpr int GRP = 32 / H;  // lanes per head within the 32-col group
#pragma unroll
  for (int r = 0; r < 4; ++r) {
    int gr = row0 + ty + r * 8;
    if (gr < M) {
      ushort4 cs;
      cs.x = f2bf(acc[r].x);
      cs.y = f2bf(acc[r].y);
      cs.z = f2bf(acc[r].z);
      cs.w = f2bf(acc[r].w);
      *(ushort4*)(Cbf + (size_t)gr * 128 + tx * 4) = cs;
    }
    float ps = acc[r].x * vs.x + acc[r].y * vs.y + acc[r].z * vs.z + acc[r].w * vs.w;
    float pd = acc[r].x * vd.x + acc[r].y * vd.y + acc[r].z * vd.z + acc[r].w * vd.w;
#pragma unroll
    for (int off = 1; off < GRP; off <<= 1) {
      ps += __shfl_xor(ps, off, 64);
      pd += __shfl_xor(pd, off, 64);
    }
    if ((tx & (GRP - 1)) == 0 && gr < M) {
      int hd = tx / GRP;
      asrc[(size_t)gr * H + hd] = ps;
      adst[(size_t)gr * H + hd] = pd;
    }
  }
}

// ---------------- Pass A: edge-parallel denominator accumulation ------------
// No max-shift: scores are O(+-5), exp safe in fp32, e/sum(e) identical to the
// max-shifted reference. denom (<=3.2MB) is L2-resident.

template <int H>
__global__ __launch_bounds__(256) void edge_denom_kernel(
    const int* __restrict__ src, const int* __restrict__ dst,
    const float* __restrict__ asrc, const float* __restrict__ adst,
    float* __restrict__ denom, int E) {
  int e = blockIdx.x * 256 + threadIdx.x;
  if (e >= E) return;
  int s = src[e], d = dst[e];
  if constexpr (H == 4) {
    float4 a = *(const float4*)(asrc + (size_t)s * 4);
    float4 b = *(const float4*)(adst + (size_t)d * 4);
    float v[4] = {a.x + b.x, a.y + b.y, a.z + b.z, a.w + b.w};
#pragma unroll
    for (int k = 0; k < 4; ++k) {
      float x = v[k];
      x = (x > 0.f) ? x : NEG_SLOPE * x;
      atomicAdd(&denom[(size_t)d * 4 + k], __expf(x));
    }
  } else {
    float x = asrc[s] + adst[d];
    x = (x > 0.f) ? x : NEG_SLOPE * x;
    atomicAdd(&denom[d], __expf(x));
  }
}

// ---------------- Pass B: wave per node, bf16 gather + recompute exp --------
// h rows are bf16 (256 B/row, 51 MB table -> L2/L3 resident). Chain:
// row_ptr -> col -> {asrc gather, h gather} -> exp -> fma; 4 edges in flight.

template <int H, bool RELU, bool LNPOOL>
__global__ __launch_bounds__(256) void gat_agg2_kernel(
    const unsigned short* __restrict__ h, const float* __restrict__ asrc,
    const float* __restrict__ adst, const float* __restrict__ denom,
    const int* __restrict__ row_ptr, const int* __restrict__ col,
    const float* __restrict__ bias, const float* __restrict__ gamma,
    const float* __restrict__ beta, const int* __restrict__ batch,
    unsigned short* __restrict__ outbf, float* __restrict__ outf,
    float* __restrict__ cnt, int n) {
  int node = (blockIdx.x * 256 + threadIdx.x) >> 6;
  int lane = threadIdx.x & 63;
  if (node >= n) return;
  int e0 = row_ptr[node];
  int ned = row_ptr[node + 1] - e0;  // real edges (self loop handled inline)

  int c0 = lane * 2;
  const int hd = (H == 1) ? 0 : (lane >> 4);  // 32 channels per head

  // my head's adst, self-loop exp, total denominator
  float adH = (H == 4) ? adst[(size_t)node * 4 + hd] : adst[node];
  float selfe;
  {
    float as_ = (H == 4) ? asrc[(size_t)node * 4 + hd] : asrc[node];
    float x = as_ + adH;
    x = (x > 0.f) ? x : NEG_SLOPE * x;
    selfe = __expf(x);
  }
  float dd = ((H == 4) ? denom[(size_t)node * 4 + hd] : denom[node]) + selfe;
  float inv_dd = 1.f / dd;

  // self contribution
  float2 acc;
  {
    unsigned hv = *(const unsigned*)(h + (size_t)node * 128 + c0);
    acc.x = bf2f((unsigned short)(hv & 0xffffu)) * selfe;
    acc.y = bf2f((unsigned short)(hv >> 16)) * selfe;
  }

  // edge loop, 4-wide: 4 col loads -> 4 asrc gathers + 4 h gathers in flight
  // -> 4 exps -> accumulate. Invalid slots get weight 0 (safe addr).
#pragma unroll 1
  for (int t = 0; t < ned; t += 4) {
    int s4[4];
    bool v4[4];
#pragma unroll
    for (int i = 0; i < 4; ++i) {
      int e = t + i;
      v4[i] = e < ned;  // wave-uniform
      s4[i] = v4[i] ? col[e0 + e] : node;
    }
    float a4[4];
    unsigned hu4[4];
#pragma unroll
    for (int i = 0; i < 4; ++i) {
      a4[i] = (H == 4) ? asrc[(size_t)s4[i] * 4 + hd] : asrc[s4[i]];
      hu4[i] = *(const unsigned*)(h + (size_t)s4[i] * 128 + c0);
    }
#pragma unroll
    for (int i = 0; i < 4; ++i) {
      float x = a4[i] + adH;
      x = (x > 0.f) ? x : NEG_SLOPE * x;
      float ee = v4[i] ? __expf(x) : 0.f;
      acc.x = fmaf(bf2f((unsigned short)(hu4[i] & 0xffffu)), ee, acc.x);
      acc.y = fmaf(bf2f((unsigned short)(hu4[i] >> 16)), ee, acc.y);
    }
  }

  acc.x = fmaf(acc.x, inv_dd, bias[c0]);
  acc.y = fmaf(acc.y, inv_dd, bias[c0 + 1]);
  if (RELU) {
    acc.x = fmaxf(acc.x, 0.f);
    acc.y = fmaxf(acc.y, 0.f);
  }
  if (!LNPOOL) {
    unsigned pv = (unsigned)f2bf(acc.x) | ((unsigned)f2bf(acc.y) << 16);
    *(unsigned*)(outbf + (size_t)node * 128 + c0) = pv;
  } else {
    // LayerNorm across 128 channels held by the wave (2/lane)
    float ssum = acc.x + acc.y;
#pragma unroll
    for (int off = 1; off < 64; off <<= 1) ssum += __shfl_xor(ssum, off, 64);
    float mu = ssum * (1.f / 128.f);
    float dx = acc.x - mu, dy = acc.y - mu;
    float vs2 = dx * dx + dy * dy;
#pragma unroll
    for (int off = 1; off < 64; off <<= 1) vs2 += __shfl_xor(vs2, off, 64);
    float inv = rsqrtf(vs2 * (1.f / 128.f) + LN_EPS);
    float ox = dx * inv * gamma[c0] + beta[c0];
    float oy = dy * inv * gamma[c0 + 1] + beta[c0 + 1];
    int g = batch[node];
    atomicAdd(&outf[(size_t)g * 128 + c0], ox);
    atomicAdd(&outf[(size_t)g * 128 + c0 + 1], oy);
    if (lane == 0) atomicAdd(&cnt[g], 1.0f);
  }
}

__global__ __launch_bounds__(256) void pool_div_kernel(float* __restrict__ out,
                                                       const float* __restrict__ cnt,
                                                       int total) {
  int i = blockIdx.x * 256 + threadIdx.x;
  if (i < total) out[i] = out[i] / fmaxf(cnt[i >> 7], 1.0f);
}

// ---------------- launch ----------------

extern "C" void kernel_launch(void* const* d_in, const int* in_sizes, int n_in,
                              void* d_out, int out_size, void* d_ws, size_t ws_size,
                              hipStream_t stream) {
  const float* x = (const float*)d_in[0];
  const int* ei = (const int*)d_in[1];
  const int* batch = (const int*)d_in[2];
  const float* W1 = (const float*)d_in[3];
  const float* att_src1 = (const float*)d_in[4];
  const float* att_dst1 = (const float*)d_in[5];
  const float* b1 = (const float*)d_in[6];
  const float* W2 = (const float*)d_in[7];
  const float* att_src2 = (const float*)d_in[8];
  const float* att_dst2 = (const float*)d_in[9];
  const float* b2 = (const float*)d_in[10];
  const float* gamma = (const float*)d_in[11];
  const float* beta = (const float*)d_in[12];
  float* out = (float*)d_out;

  const int N = N_NODES_C, E = N_EDGES_C, G = NUM_GRAPHS_C;
  const int* src = ei;
  const int* dst = ei + E;

  float* p = (float*)d_ws;
  float* asrc1 = p; p += (size_t)N * 4;
  float* adst1 = p; p += (size_t)N * 4;
  float* asrc2 = p; p += N;
  float* adst2 = p; p += N;
  float* den1 = p;  p += (size_t)N * 4;
  float* den2 = p;  p += N;
  float* cnt = p;   p += G;
  int* ip = (int*)p;
  int* deg = ip;     ip += N;
  int* cursor = ip;  ip += N;
  int* col = ip;     ip += E;
  int* bsums = ip;   ip += 256;
  int* bsums2 = ip;  ip += 256;
  int* row_ptr = ip; ip += N + 2;  // +pad to keep 8B alignment downstream
  unsigned short* h1bf = (unsigned short*)ip;          // [N*128] bf16
  unsigned short* hbbf = h1bf + (size_t)N * 128;       // [N*128] bf16
  unsigned short* h2bf = hbbf + (size_t)N * 128;       // [N*128] bf16
  (void)ws_size; (void)in_sizes; (void)n_in; (void)out_size;

  hipMemsetAsync(deg, 0, sizeof(int) * (size_t)N, stream);
  hipMemsetAsync(cursor, 0, sizeof(int) * (size_t)N, stream);
  hipMemsetAsync(cnt, 0, sizeof(float) * (size_t)G, stream);
  hipMemsetAsync(den1, 0, sizeof(float) * (size_t)N * 4, stream);
  hipMemsetAsync(den2, 0, sizeof(float) * (size_t)N, stream);
  hipMemsetAsync(d_out, 0, sizeof(float) * (size_t)G * 128, stream);

  // CSR by destination
  count_deg_kernel<<<(E + 255) / 256, 256, 0, stream>>>(dst, deg, E);
  int nblk = (N + 1023) / 1024;
  scan_kernel<<<nblk, 256, 0, stream>>>(deg, row_ptr, bsums, N);
  scan_kernel<<<1, 256, 0, stream>>>(bsums, bsums2, nullptr, nblk);
  scan_addoff_kernel<<<nblk, 256, 0, stream>>>(row_ptr, bsums2, N, E);
  fill_csr_kernel<<<(E + 255) / 256, 256, 0, stream>>>(src, dst, row_ptr, cursor, col, E);

  int wblocks = (int)(((size_t)N * 64 + 255) / 256);  // wave per node
  int eblocks = (E + 255) / 256;

  // Layer 1: GAT(128 -> 4x32), ReLU
  gemm_att<4, false><<<(N + 31) / 32, 256, 0, stream>>>(
      x, W1, att_src1, att_dst1, h1bf, asrc1, adst1, N);
  edge_denom_kernel<4><<<eblocks, 256, 0, stream>>>(src, dst, asrc1, adst1, den1, E);
  gat_agg2_kernel<4, true, false><<<wblocks, 256, 0, stream>>>(
      h1bf, asrc1, adst1, den1, row_ptr, col, b1, nullptr, nullptr, nullptr,
      hbbf, nullptr, nullptr, N);

  // Layer 2: GAT(128 -> 1x128) + LayerNorm + mean-pool (fused into epilogue)
  gemm_att<1, true><<<(N + 31) / 32, 256, 0, stream>>>(
      hbbf, W2, att_src2, att_dst2, h2bf, asrc2, adst2, N);
  edge_denom_kernel<1><<<eblocks, 256, 0, stream>>>(src, dst, asrc2, adst2, den2, E);
  gat_agg2_kernel<1, false, true><<<wblocks, 256, 0, stream>>>(
      h2bf, asrc2, adst2, den2, row_ptr, col, b2, gamma, beta, batch,
      nullptr, out, cnt, N);

  pool_div_kernel<<<(G * 128 + 255) / 256, 256, 0, stream>>>(out, cnt, G * 128);
}

// Round 10
// 713.538 us; speedup vs baseline: 1.0590x; 1.0151x over previous
//
#include <hip/hip_runtime.h>
#include <cstdint>
#include <cstddef>

#define N_NODES_C 200000
#define N_EDGES_C 600000
#define NUM_GRAPHS_C 20000

constexpr float NEG_SLOPE = 0.2f;
constexpr float LN_EPS = 1e-5f;

// bf16 helpers (RNE)
static __device__ __forceinline__ unsigned short f2bf(float f) {
  unsigned u = __float_as_uint(f);
  u = (u + 0x7fffu + ((u >> 16) & 1u)) >> 16;
  return (unsigned short)u;
}
static __device__ __forceinline__ float bf2f(unsigned short s) {
  return __uint_as_float(((unsigned)s) << 16);
}

// ---------------- CSR build ----------------

__global__ __launch_bounds__(256) void count_deg_kernel(const int* __restrict__ dst,
                                                        int* __restrict__ deg, int E) {
  int e = blockIdx.x * 256 + threadIdx.x;
  if (e < E) atomicAdd(&deg[dst[e]], 1);
}

// exclusive scan, 1024 elements per block (256 threads x 4)
__global__ __launch_bounds__(256) void scan_kernel(const int* __restrict__ in,
                                                   int* __restrict__ out,
                                                   int* __restrict__ bsums, int n) {
  __shared__ int ss[256];
  int t = threadIdx.x;
  int base = blockIdx.x * 1024 + t * 4;
  int v[4];
  int s = 0;
#pragma unroll
  for (int j = 0; j < 4; ++j) {
    v[j] = (base + j < n) ? in[base + j] : 0;
    s += v[j];
  }
  ss[t] = s;
  __syncthreads();
  for (int off = 1; off < 256; off <<= 1) {
    int x = (t >= off) ? ss[t - off] : 0;
    __syncthreads();
    ss[t] += x;
    __syncthreads();
  }
  int incl = ss[t];
  int excl = incl - s;
  if (bsums != nullptr && t == 255) bsums[blockIdx.x] = incl;
  int run = excl;
#pragma unroll
  for (int j = 0; j < 4; ++j) {
    if (base + j < n) out[base + j] = run;
    run += v[j];
  }
}

__global__ __launch_bounds__(256) void scan_addoff_kernel(int* __restrict__ data,
                                                          const int* __restrict__ boff,
                                                          int n, int total) {
  int base = blockIdx.x * 1024 + threadIdx.x * 4;
  int add = boff[blockIdx.x];
#pragma unroll
  for (int j = 0; j < 4; ++j) {
    if (base + j < n) data[base + j] += add;
  }
  if (blockIdx.x == 0 && threadIdx.x == 0) data[n] = total;
}

__global__ __launch_bounds__(256) void fill_csr_kernel(const int* __restrict__ src,
                                                       const int* __restrict__ dst,
                                                       const int* __restrict__ row_ptr,
                                                       int* __restrict__ cursor,
                                                       int* __restrict__ col, int E) {
  int e = blockIdx.x * 256 + threadIdx.x;
  if (e < E) {
    int d = dst[e];
    int p = atomicAdd(&cursor[d], 1);
    col[row_ptr[d] + p] = src[e];
  }
}

// ---------------- GEMM + att-score epilogue ----------------
// C[M,128] = A[M,128] @ W[128,128]; C written as bf16 (gather/table dtype);
// asrc/adst computed fp32 from the fp32 accumulators. A is fp32 (layer 1)
// or bf16 (layer 2, converted to fp32 while staging into LDS).

template <int H, bool A_BF16>
__global__ __launch_bounds__(256) void gemm_att(const void* __restrict__ Av,
                                                const float* __restrict__ W,
                                                const float* __restrict__ att_src,
                                                const float* __restrict__ att_dst,
                                                unsigned short* __restrict__ Cbf,
                                                float* __restrict__ asrc,
                                                float* __restrict__ adst, int M) {
  __shared__ float As[32][32];
  __shared__ float Ws[32][128];
  int tid = threadIdx.x;
  int tx = tid & 31;   // col group (4 cols)
  int ty = tid >> 5;   // 0..7
  int row0 = blockIdx.x * 32;
  float4 acc[4];
#pragma unroll
  for (int r = 0; r < 4; ++r) acc[r] = make_float4(0.f, 0.f, 0.f, 0.f);

#pragma unroll 1
  for (int k0 = 0; k0 < 128; k0 += 32) {
    {
      int r = tid >> 3;
      int c4 = tid & 7;
      int gr = row0 + r;
      if constexpr (A_BF16) {
        const unsigned short* A = (const unsigned short*)Av;
        ushort4 v = make_ushort4(0, 0, 0, 0);
        if (gr < M) v = *(const ushort4*)(A + (size_t)gr * 128 + k0 + c4 * 4);
        As[r][c4 * 4 + 0] = bf2f(v.x);
        As[r][c4 * 4 + 1] = bf2f(v.y);
        As[r][c4 * 4 + 2] = bf2f(v.z);
        As[r][c4 * 4 + 3] = bf2f(v.w);
      } else {
        const float* A = (const float*)Av;
        float4 v = make_float4(0.f, 0.f, 0.f, 0.f);
        if (gr < M) v = *(const float4*)(A + (size_t)gr * 128 + k0 + c4 * 4);
        *(float4*)&As[r][c4 * 4] = v;
      }
    }
#pragma unroll
    for (int i = 0; i < 4; ++i) {
      int idx = tid + i * 256;
      int r = idx >> 5;
      int c4 = idx & 31;
      *(float4*)&Ws[r][c4 * 4] = *(const float4*)(W + (size_t)(k0 + r) * 128 + c4 * 4);
    }
    __syncthreads();
#pragma unroll
    for (int kk = 0; kk < 32; ++kk) {
      float4 w = *(const float4*)&Ws[kk][tx * 4];
#pragma unroll
      for (int r = 0; r < 4; ++r) {
        float a = As[ty + r * 8][kk];
        acc[r].x = fmaf(a, w.x, acc[r].x);
        acc[r].y = fmaf(a, w.y, acc[r].y);
        acc[r].z = fmaf(a, w.z, acc[r].z);
        acc[r].w = fmaf(a, w.w, acc[r].w);
      }
    }
    __syncthreads();
  }

  float4 vs = *(const float4*)(att_src + tx * 4);
  float4 vd = *(const float4*)(att_dst + tx * 4);
  constexpr int GRP = 32 / H;  // lanes per head within the 32-col group
#pragma unroll
  for (int r = 0; r < 4; ++r) {
    int gr = row0 + ty + r * 8;
    if (gr < M) {
      ushort4 cs;
      cs.x = f2bf(acc[r].x);
      cs.y = f2bf(acc[r].y);
      cs.z = f2bf(acc[r].z);
      cs.w = f2bf(acc[r].w);
      *(ushort4*)(Cbf + (size_t)gr * 128 + tx * 4) = cs;
    }
    float ps = acc[r].x * vs.x + acc[r].y * vs.y + acc[r].z * vs.z + acc[r].w * vs.w;
    float pd = acc[r].x * vd.x + acc[r].y * vd.y + acc[r].z * vd.z + acc[r].w * vd.w;
#pragma unroll
    for (int off = 1; off < GRP; off <<= 1) {
      ps += __shfl_xor(ps, off, 64);
      pd += __shfl_xor(pd, off, 64);
    }
    if ((tx & (GRP - 1)) == 0 && gr < M) {
      int hd = tx / GRP;
      asrc[(size_t)gr * H + hd] = ps;
      adst[(size_t)gr * H + hd] = pd;
    }
  }
}

// ---------------- Pass A: edge-parallel denominator accumulation ------------

template <int H>
__global__ __launch_bounds__(256) void edge_denom_kernel(
    const int* __restrict__ src, const int* __restrict__ dst,
    const float* __restrict__ asrc, const float* __restrict__ adst,
    float* __restrict__ denom, int E) {
  int e = blockIdx.x * 256 + threadIdx.x;
  if (e >= E) return;
  int s = src[e], d = dst[e];
  if constexpr (H == 4) {
    float4 a = *(const float4*)(asrc + (size_t)s * 4);
    float4 b = *(const float4*)(adst + (size_t)d * 4);
    float v[4] = {a.x + b.x, a.y + b.y, a.z + b.z, a.w + b.w};
#pragma unroll
    for (int k = 0; k < 4; ++k) {
      float x = v[k];
      x = (x > 0.f) ? x : NEG_SLOPE * x;
      atomicAdd(&denom[(size_t)d * 4 + k], __expf(x));
    }
  } else {
    float x = asrc[s] + adst[d];
    x = (x > 0.f) ? x : NEG_SLOPE * x;
    atomicAdd(&denom[d], __expf(x));
  }
}

// ---------------- Pass B: TWO nodes per wave, bf16 gather + recompute exp ---
// Each wave owns nodes A=2*wid, B=2*wid+1, full 64-lane channel width for
// both. Two independent dependency chains -> 2x loads in flight per memory
// epoch (the round-4..9 limiter was per-wave MLP, not bytes or ALU).
// All state in named scalars / fully-unrolled 4-arrays (no scratch).

template <int H, bool RELU, bool LNPOOL>
__global__ __launch_bounds__(256) void gat_agg3_kernel(
    const unsigned short* __restrict__ h, const float* __restrict__ asrc,
    const float* __restrict__ adst, const float* __restrict__ denom,
    const int* __restrict__ row_ptr, const int* __restrict__ col,
    const float* __restrict__ bias, const float* __restrict__ gamma,
    const float* __restrict__ beta, const int* __restrict__ batch,
    unsigned short* __restrict__ outbf, float* __restrict__ outf,
    float* __restrict__ cnt, int n) {
  int wid = (blockIdx.x * 256 + threadIdx.x) >> 6;
  int lane = threadIdx.x & 63;
  int nodeA = wid * 2;
  int nodeB = nodeA + 1;
  if (nodeA >= n) return;
  bool hasB = nodeB < n;

  int e0A = row_ptr[nodeA];
  int e1A = row_ptr[nodeA + 1];
  int e1B = hasB ? row_ptr[nodeB + 1] : e1A;
  int e0B = e1A;  // CSR rows are contiguous
  int nedA = e1A - e0A;
  int nedB = e1B - e0B;

  int c0 = lane * 2;
  const int hd = (H == 1) ? 0 : (lane >> 4);

  // per-node head scores / self exp / denom
  float adA = (H == 4) ? adst[(size_t)nodeA * 4 + hd] : adst[nodeA];
  float asA = (H == 4) ? asrc[(size_t)nodeA * 4 + hd] : asrc[nodeA];
  int nB = hasB ? nodeB : nodeA;
  float adB = (H == 4) ? adst[(size_t)nB * 4 + hd] : adst[nB];
  float asB = (H == 4) ? asrc[(size_t)nB * 4 + hd] : asrc[nB];

  float xA = asA + adA; xA = (xA > 0.f) ? xA : NEG_SLOPE * xA;
  float selfeA = __expf(xA);
  float xB = asB + adB; xB = (xB > 0.f) ? xB : NEG_SLOPE * xB;
  float selfeB = __expf(xB);

  float ddA = ((H == 4) ? denom[(size_t)nodeA * 4 + hd] : denom[nodeA]) + selfeA;
  float ddB = ((H == 4) ? denom[(size_t)nB * 4 + hd] : denom[nB]) + selfeB;
  float invA = 1.f / ddA;
  float invB = 1.f / ddB;

  // self contributions
  float2 accA, accB;
  {
    unsigned ha = *(const unsigned*)(h + (size_t)nodeA * 128 + c0);
    unsigned hb = *(const unsigned*)(h + (size_t)nB * 128 + c0);
    accA.x = bf2f((unsigned short)(ha & 0xffffu)) * selfeA;
    accA.y = bf2f((unsigned short)(ha >> 16)) * selfeA;
    accB.x = bf2f((unsigned short)(hb & 0xffffu)) * selfeB;
    accB.y = bf2f((unsigned short)(hb >> 16)) * selfeB;
  }

  // interleaved edge loop, 4-wide per node: up to 16 loads in flight
  int tmax = (nedA > nedB) ? nedA : nedB;
#pragma unroll 1
  for (int t = 0; t < tmax; t += 4) {
    int sA4[4], sB4[4];
    bool vA4[4], vB4[4];
#pragma unroll
    for (int i = 0; i < 4; ++i) {
      int e = t + i;
      vA4[i] = e < nedA;
      vB4[i] = hasB && e < nedB;
      sA4[i] = vA4[i] ? col[e0A + e] : nodeA;
      sB4[i] = vB4[i] ? col[e0B + e] : nodeA;
    }
    float aA4[4], aB4[4];
    unsigned hA4[4], hB4[4];
#pragma unroll
    for (int i = 0; i < 4; ++i) {
      aA4[i] = (H == 4) ? asrc[(size_t)sA4[i] * 4 + hd] : asrc[sA4[i]];
      aB4[i] = (H == 4) ? asrc[(size_t)sB4[i] * 4 + hd] : asrc[sB4[i]];
      hA4[i] = *(const unsigned*)(h + (size_t)sA4[i] * 128 + c0);
      hB4[i] = *(const unsigned*)(h + (size_t)sB4[i] * 128 + c0);
    }
#pragma unroll
    for (int i = 0; i < 4; ++i) {
      float ya = aA4[i] + adA; ya = (ya > 0.f) ? ya : NEG_SLOPE * ya;
      float eeA = vA4[i] ? __expf(ya) : 0.f;
      float yb = aB4[i] + adB; yb = (yb > 0.f) ? yb : NEG_SLOPE * yb;
      float eeB = vB4[i] ? __expf(yb) : 0.f;
      accA.x = fmaf(bf2f((unsigned short)(hA4[i] & 0xffffu)), eeA, accA.x);
      accA.y = fmaf(bf2f((unsigned short)(hA4[i] >> 16)), eeA, accA.y);
      accB.x = fmaf(bf2f((unsigned short)(hB4[i] & 0xffffu)), eeB, accB.x);
      accB.y = fmaf(bf2f((unsigned short)(hB4[i] >> 16)), eeB, accB.y);
    }
  }

  float bx = bias[c0], by = bias[c0 + 1];
  accA.x = fmaf(accA.x, invA, bx);
  accA.y = fmaf(accA.y, invA, by);
  accB.x = fmaf(accB.x, invB, bx);
  accB.y = fmaf(accB.y, invB, by);
  if (RELU) {
    accA.x = fmaxf(accA.x, 0.f); accA.y = fmaxf(accA.y, 0.f);
    accB.x = fmaxf(accB.x, 0.f); accB.y = fmaxf(accB.y, 0.f);
  }

  if (!LNPOOL) {
    unsigned pa = (unsigned)f2bf(accA.x) | ((unsigned)f2bf(accA.y) << 16);
    *(unsigned*)(outbf + (size_t)nodeA * 128 + c0) = pa;
    if (hasB) {
      unsigned pb = (unsigned)f2bf(accB.x) | ((unsigned)f2bf(accB.y) << 16);
      *(unsigned*)(outbf + (size_t)nodeB * 128 + c0) = pb;
    }
  } else {
    // LayerNorm + pool for A and B (independent shfl chains, interleaved)
    float sA = accA.x + accA.y;
    float sB = accB.x + accB.y;
#pragma unroll
    for (int off = 1; off < 64; off <<= 1) {
      sA += __shfl_xor(sA, off, 64);
      sB += __shfl_xor(sB, off, 64);
    }
    float muA = sA * (1.f / 128.f), muB = sB * (1.f / 128.f);
    float dxA = accA.x - muA, dyA = accA.y - muA;
    float dxB = accB.x - muB, dyB = accB.y - muB;
    float vA = dxA * dxA + dyA * dyA;
    float vB = dxB * dxB + dyB * dyB;
#pragma unroll
    for (int off = 1; off < 64; off <<= 1) {
      vA += __shfl_xor(vA, off, 64);
      vB += __shfl_xor(vB, off, 64);
    }
    float ivA = rsqrtf(vA * (1.f / 128.f) + LN_EPS);
    float ivB = rsqrtf(vB * (1.f / 128.f) + LN_EPS);
    float gx = gamma[c0], gy = gamma[c0 + 1];
    float ex = beta[c0], ey = beta[c0 + 1];
    int gA = batch[nodeA];
    atomicAdd(&outf[(size_t)gA * 128 + c0], dxA * ivA * gx + ex);
    atomicAdd(&outf[(size_t)gA * 128 + c0 + 1], dyA * ivA * gy + ey);
    if (lane == 0) atomicAdd(&cnt[gA], 1.0f);
    if (hasB) {
      int gB = batch[nodeB];
      atomicAdd(&outf[(size_t)gB * 128 + c0], dxB * ivB * gx + ex);
      atomicAdd(&outf[(size_t)gB * 128 + c0 + 1], dyB * ivB * gy + ey);
      if (lane == 0) atomicAdd(&cnt[gB], 1.0f);
    }
  }
}

__global__ __launch_bounds__(256) void pool_div_kernel(float* __restrict__ out,
                                                       const float* __restrict__ cnt,
                                                       int total) {
  int i = blockIdx.x * 256 + threadIdx.x;
  if (i < total) out[i] = out[i] / fmaxf(cnt[i >> 7], 1.0f);
}

// ---------------- launch ----------------

extern "C" void kernel_launch(void* const* d_in, const int* in_sizes, int n_in,
                              void* d_out, int out_size, void* d_ws, size_t ws_size,
                              hipStream_t stream) {
  const float* x = (const float*)d_in[0];
  const int* ei = (const int*)d_in[1];
  const int* batch = (const int*)d_in[2];
  const float* W1 = (const float*)d_in[3];
  const float* att_src1 = (const float*)d_in[4];
  const float* att_dst1 = (const float*)d_in[5];
  const float* b1 = (const float*)d_in[6];
  const float* W2 = (const float*)d_in[7];
  const float* att_src2 = (const float*)d_in[8];
  const float* att_dst2 = (const float*)d_in[9];
  const float* b2 = (const float*)d_in[10];
  const float* gamma = (const float*)d_in[11];
  const float* beta = (const float*)d_in[12];
  float* out = (float*)d_out;

  const int N = N_NODES_C, E = N_EDGES_C, G = NUM_GRAPHS_C;
  const int* src = ei;
  const int* dst = ei + E;

  float* p = (float*)d_ws;
  float* asrc1 = p; p += (size_t)N * 4;
  float* adst1 = p; p += (size_t)N * 4;
  float* asrc2 = p; p += N;
  float* adst2 = p; p += N;
  float* den1 = p;  p += (size_t)N * 4;
  float* den2 = p;  p += N;
  float* cnt = p;   p += G;
  int* ip = (int*)p;
  int* deg = ip;     ip += N;
  int* cursor = ip;  ip += N;
  int* col = ip;     ip += E;
  int* bsums = ip;   ip += 256;
  int* bsums2 = ip;  ip += 256;
  int* row_ptr = ip; ip += N + 2;  // +pad to keep 8B alignment downstream
  unsigned short* h1bf = (unsigned short*)ip;          // [N*128] bf16
  unsigned short* hbbf = h1bf + (size_t)N * 128;       // [N*128] bf16
  unsigned short* h2bf = hbbf + (size_t)N * 128;       // [N*128] bf16
  (void)ws_size; (void)in_sizes; (void)n_in; (void)out_size;

  hipMemsetAsync(deg, 0, sizeof(int) * (size_t)N, stream);
  hipMemsetAsync(cursor, 0, sizeof(int) * (size_t)N, stream);
  hipMemsetAsync(cnt, 0, sizeof(float) * (size_t)G, stream);
  hipMemsetAsync(den1, 0, sizeof(float) * (size_t)N * 4, stream);
  hipMemsetAsync(den2, 0, sizeof(float) * (size_t)N, stream);
  hipMemsetAsync(d_out, 0, sizeof(float) * (size_t)G * 128, stream);

  // CSR by destination
  count_deg_kernel<<<(E + 255) / 256, 256, 0, stream>>>(dst, deg, E);
  int nblk = (N + 1023) / 1024;
  scan_kernel<<<nblk, 256, 0, stream>>>(deg, row_ptr, bsums, N);
  scan_kernel<<<1, 256, 0, stream>>>(bsums, bsums2, nullptr, nblk);
  scan_addoff_kernel<<<nblk, 256, 0, stream>>>(row_ptr, bsums2, N, E);
  fill_csr_kernel<<<(E + 255) / 256, 256, 0, stream>>>(src, dst, row_ptr, cursor, col, E);

  int pairs = (N + 1) / 2;
  int pblocks = (int)(((size_t)pairs * 64 + 255) / 256);  // 2 nodes per wave
  int eblocks = (E + 255) / 256;

  // Layer 1: GAT(128 -> 4x32), ReLU
  gemm_att<4, false><<<(N + 31) / 32, 256, 0, stream>>>(
      x, W1, att_src1, att_dst1, h1bf, asrc1, adst1, N);
  edge_denom_kernel<4><<<eblocks, 256, 0, stream>>>(src, dst, asrc1, adst1, den1, E);
  gat_agg3_kernel<4, true, false><<<pblocks, 256, 0, stream>>>(
      h1bf, asrc1, adst1, den1, row_ptr, col, b1, nullptr, nullptr, nullptr,
      hbbf, nullptr, nullptr, N);

  // Layer 2: GAT(128 -> 1x128) + LayerNorm + mean-pool (fused into epilogue)
  gemm_att<1, true><<<(N + 31) / 32, 256, 0, stream>>>(
      hbbf, W2, att_src2, att_dst2, h2bf, asrc2, adst2, N);
  edge_denom_kernel<1><<<eblocks, 256, 0, stream>>>(src, dst, asrc2, adst2, den2, E);
  gat_agg3_kernel<1, false, true><<<pblocks, 256, 0, stream>>>(
      h2bf, asrc2, adst2, den2, row_ptr, col, b2, gamma, beta, batch,
      nullptr, out, cnt, N);

  pool_div_kernel<<<(G * 128 + 255) / 256, 256, 0, stream>>>(out, cnt, G * 128);
}

// Round 11
// 577.813 us; speedup vs baseline: 1.3077x; 1.2349x over previous
//
#include <hip/hip_runtime.h>
#include <cstdint>
#include <cstddef>

#define N_NODES_C 200000
#define N_EDGES_C 600000
#define NUM_GRAPHS_C 20000

constexpr float NEG_SLOPE = 0.2f;
constexpr float LN_EPS = 1e-5f;

// bf16 helpers (RNE)
static __device__ __forceinline__ unsigned short f2bf(float f) {
  unsigned u = __float_as_uint(f);
  u = (u + 0x7fffu + ((u >> 16) & 1u)) >> 16;
  return (unsigned short)u;
}
static __device__ __forceinline__ float bf2f(unsigned short s) {
  return __uint_as_float(((unsigned)s) << 16);
}

// ---------------- CSR build ----------------

__global__ __launch_bounds__(256) void count_deg_kernel(const int* __restrict__ dst,
                                                        int* __restrict__ deg, int E) {
  int e = blockIdx.x * 256 + threadIdx.x;
  if (e < E) atomicAdd(&deg[dst[e]], 1);
}

// exclusive scan, 1024 elements per block (256 threads x 4)
__global__ __launch_bounds__(256) void scan_kernel(const int* __restrict__ in,
                                                   int* __restrict__ out,
                                                   int* __restrict__ bsums, int n) {
  __shared__ int ss[256];
  int t = threadIdx.x;
  int base = blockIdx.x * 1024 + t * 4;
  int v[4];
  int s = 0;
#pragma unroll
  for (int j = 0; j < 4; ++j) {
    v[j] = (base + j < n) ? in[base + j] : 0;
    s += v[j];
  }
  ss[t] = s;
  __syncthreads();
  for (int off = 1; off < 256; off <<= 1) {
    int x = (t >= off) ? ss[t - off] : 0;
    __syncthreads();
    ss[t] += x;
    __syncthreads();
  }
  int incl = ss[t];
  int excl = incl - s;
  if (bsums != nullptr && t == 255) bsums[blockIdx.x] = incl;
  int run = excl;
#pragma unroll
  for (int j = 0; j < 4; ++j) {
    if (base + j < n) out[base + j] = run;
    run += v[j];
  }
}

__global__ __launch_bounds__(256) void scan_addoff_kernel(int* __restrict__ data,
                                                          const int* __restrict__ boff,
                                                          int n, int total) {
  int base = blockIdx.x * 1024 + threadIdx.x * 4;
  int add = boff[blockIdx.x];
#pragma unroll
  for (int j = 0; j < 4; ++j) {
    if (base + j < n) data[base + j] += add;
  }
  if (blockIdx.x == 0 && threadIdx.x == 0) data[n] = total;
}

__global__ __launch_bounds__(256) void fill_csr_kernel(const int* __restrict__ src,
                                                       const int* __restrict__ dst,
                                                       const int* __restrict__ row_ptr,
                                                       int* __restrict__ cursor,
                                                       int* __restrict__ col, int E) {
  int e = blockIdx.x * 256 + threadIdx.x;
  if (e < E) {
    int d = dst[e];
    int p = atomicAdd(&cursor[d], 1);
    col[row_ptr[d] + p] = src[e];
  }
}

// ---------------- graph_ptr from sorted batch (boundary detect) ----------------
// gp has G+1 entries; empty graphs get zero-length ranges.

__global__ __launch_bounds__(256) void graph_ptr_kernel(const int* __restrict__ batch,
                                                        int* __restrict__ gp, int n,
                                                        int G) {
  int i = blockIdx.x * 256 + threadIdx.x;
  if (i < n) {
    int prev = (i == 0) ? -1 : batch[i - 1];
    int cur = batch[i];
#pragma unroll 1
    for (int g = prev + 1; g <= cur; ++g) gp[g] = i;
  } else if (i == n) {
    int last = batch[n - 1];
#pragma unroll 1
    for (int g = last + 1; g <= G; ++g) gp[g] = n;
  }
}

// ---------------- GEMM + att-score epilogue ----------------
// C[M,128] = A[M,128] @ W[128,128]; C written as bf16 (gather/table dtype);
// asrc/adst computed fp32 from the fp32 accumulators. A is fp32 (layer 1)
// or bf16 (layer 2, converted to fp32 while staging into LDS).

template <int H, bool A_BF16>
__global__ __launch_bounds__(256) void gemm_att(const void* __restrict__ Av,
                                                const float* __restrict__ W,
                                                const float* __restrict__ att_src,
                                                const float* __restrict__ att_dst,
                                                unsigned short* __restrict__ Cbf,
                                                float* __restrict__ asrc,
                                                float* __restrict__ adst, int M) {
  __shared__ float As[32][32];
  __shared__ float Ws[32][128];
  int tid = threadIdx.x;
  int tx = tid & 31;   // col group (4 cols)
  int ty = tid >> 5;   // 0..7
  int row0 = blockIdx.x * 32;
  float4 acc[4];
#pragma unroll
  for (int r = 0; r < 4; ++r) acc[r] = make_float4(0.f, 0.f, 0.f, 0.f);

#pragma unroll 1
  for (int k0 = 0; k0 < 128; k0 += 32) {
    {
      int r = tid >> 3;
      int c4 = tid & 7;
      int gr = row0 + r;
      if constexpr (A_BF16) {
        const unsigned short* A = (const unsigned short*)Av;
        ushort4 v = make_ushort4(0, 0, 0, 0);
        if (gr < M) v = *(const ushort4*)(A + (size_t)gr * 128 + k0 + c4 * 4);
        As[r][c4 * 4 + 0] = bf2f(v.x);
        As[r][c4 * 4 + 1] = bf2f(v.y);
        As[r][c4 * 4 + 2] = bf2f(v.z);
        As[r][c4 * 4 + 3] = bf2f(v.w);
      } else {
        const float* A = (const float*)Av;
        float4 v = make_float4(0.f, 0.f, 0.f, 0.f);
        if (gr < M) v = *(const float4*)(A + (size_t)gr * 128 + k0 + c4 * 4);
        *(float4*)&As[r][c4 * 4] = v;
      }
    }
#pragma unroll
    for (int i = 0; i < 4; ++i) {
      int idx = tid + i * 256;
      int r = idx >> 5;
      int c4 = idx & 31;
      *(float4*)&Ws[r][c4 * 4] = *(const float4*)(W + (size_t)(k0 + r) * 128 + c4 * 4);
    }
    __syncthreads();
#pragma unroll
    for (int kk = 0; kk < 32; ++kk) {
      float4 w = *(const float4*)&Ws[kk][tx * 4];
#pragma unroll
      for (int r = 0; r < 4; ++r) {
        float a = As[ty + r * 8][kk];
        acc[r].x = fmaf(a, w.x, acc[r].x);
        acc[r].y = fmaf(a, w.y, acc[r].y);
        acc[r].z = fmaf(a, w.z, acc[r].z);
        acc[r].w = fmaf(a, w.w, acc[r].w);
      }
    }
    __syncthreads();
  }

  float4 vs = *(const float4*)(att_src + tx * 4);
  float4 vd = *(const float4*)(att_dst + tx * 4);
  constexpr int GRP = 32 / H;  // lanes per head within the 32-col group
#pragma unroll
  for (int r = 0; r < 4; ++r) {
    int gr = row0 + ty + r * 8;
    if (gr < M) {
      ushort4 cs;
      cs.x = f2bf(acc[r].x);
      cs.y = f2bf(acc[r].y);
      cs.z = f2bf(acc[r].z);
      cs.w = f2bf(acc[r].w);
      *(ushort4*)(Cbf + (size_t)gr * 128 + tx * 4) = cs;
    }
    float ps = acc[r].x * vs.x + acc[r].y * vs.y + acc[r].z * vs.z + acc[r].w * vs.w;
    float pd = acc[r].x * vd.x + acc[r].y * vd.y + acc[r].z * vd.z + acc[r].w * vd.w;
#pragma unroll
    for (int off = 1; off < GRP; off <<= 1) {
      ps += __shfl_xor(ps, off, 64);
      pd += __shfl_xor(pd, off, 64);
    }
    if ((tx & (GRP - 1)) == 0 && gr < M) {
      int hd = tx / GRP;
      asrc[(size_t)gr * H + hd] = ps;
      adst[(size_t)gr * H + hd] = pd;
    }
  }
}

// ---------------- Pass A: edge-parallel denominator accumulation ------------

template <int H>
__global__ __launch_bounds__(256) void edge_denom_kernel(
    const int* __restrict__ src, const int* __restrict__ dst,
    const float* __restrict__ asrc, const float* __restrict__ adst,
    float* __restrict__ denom, int E) {
  int e = blockIdx.x * 256 + threadIdx.x;
  if (e >= E) return;
  int s = src[e], d = dst[e];
  if constexpr (H == 4) {
    float4 a = *(const float4*)(asrc + (size_t)s * 4);
    float4 b = *(const float4*)(adst + (size_t)d * 4);
    float v[4] = {a.x + b.x, a.y + b.y, a.z + b.z, a.w + b.w};
#pragma unroll
    for (int k = 0; k < 4; ++k) {
      float x = v[k];
      x = (x > 0.f) ? x : NEG_SLOPE * x;
      atomicAdd(&denom[(size_t)d * 4 + k], __expf(x));
    }
  } else {
    float x = asrc[s] + adst[d];
    x = (x > 0.f) ? x : NEG_SLOPE * x;
    atomicAdd(&denom[d], __expf(x));
  }
}

// ---------------- Pass B: TWO nodes per wave, bf16 gather + recompute exp ---
// LNPOOL variant now applies LayerNorm in-wave and writes the LN'd row as
// coalesced bf16 — ZERO atomics (round-10 suspect: 25.6M atomicAdd pool with
// constant 211MB WRITE_SIZE). Pooling moved to a segmented-reduction kernel.

template <int H, bool RELU, bool LNOUT>
__global__ __launch_bounds__(256) void gat_agg3_kernel(
    const unsigned short* __restrict__ h, const float* __restrict__ asrc,
    const float* __restrict__ adst, const float* __restrict__ denom,
    const int* __restrict__ row_ptr, const int* __restrict__ col,
    const float* __restrict__ bias, const float* __restrict__ gamma,
    const float* __restrict__ beta, unsigned short* __restrict__ outbf, int n) {
  int wid = (blockIdx.x * 256 + threadIdx.x) >> 6;
  int lane = threadIdx.x & 63;
  int nodeA = wid * 2;
  int nodeB = nodeA + 1;
  if (nodeA >= n) return;
  bool hasB = nodeB < n;

  int e0A = row_ptr[nodeA];
  int e1A = row_ptr[nodeA + 1];
  int e1B = hasB ? row_ptr[nodeB + 1] : e1A;
  int e0B = e1A;  // CSR rows are contiguous
  int nedA = e1A - e0A;
  int nedB = e1B - e0B;

  int c0 = lane * 2;
  const int hd = (H == 1) ? 0 : (lane >> 4);

  float adA = (H == 4) ? adst[(size_t)nodeA * 4 + hd] : adst[nodeA];
  float asA = (H == 4) ? asrc[(size_t)nodeA * 4 + hd] : asrc[nodeA];
  int nB = hasB ? nodeB : nodeA;
  float adB = (H == 4) ? adst[(size_t)nB * 4 + hd] : adst[nB];
  float asB = (H == 4) ? asrc[(size_t)nB * 4 + hd] : asrc[nB];

  float xA = asA + adA; xA = (xA > 0.f) ? xA : NEG_SLOPE * xA;
  float selfeA = __expf(xA);
  float xB = asB + adB; xB = (xB > 0.f) ? xB : NEG_SLOPE * xB;
  float selfeB = __expf(xB);

  float ddA = ((H == 4) ? denom[(size_t)nodeA * 4 + hd] : denom[nodeA]) + selfeA;
  float ddB = ((H == 4) ? denom[(size_t)nB * 4 + hd] : denom[nB]) + selfeB;
  float invA = 1.f / ddA;
  float invB = 1.f / ddB;

  float2 accA, accB;
  {
    unsigned ha = *(const unsigned*)(h + (size_t)nodeA * 128 + c0);
    unsigned hb = *(const unsigned*)(h + (size_t)nB * 128 + c0);
    accA.x = bf2f((unsigned short)(ha & 0xffffu)) * selfeA;
    accA.y = bf2f((unsigned short)(ha >> 16)) * selfeA;
    accB.x = bf2f((unsigned short)(hb & 0xffffu)) * selfeB;
    accB.y = bf2f((unsigned short)(hb >> 16)) * selfeB;
  }

  int tmax = (nedA > nedB) ? nedA : nedB;
#pragma unroll 1
  for (int t = 0; t < tmax; t += 4) {
    int sA4[4], sB4[4];
    bool vA4[4], vB4[4];
#pragma unroll
    for (int i = 0; i < 4; ++i) {
      int e = t + i;
      vA4[i] = e < nedA;
      vB4[i] = hasB && e < nedB;
      sA4[i] = vA4[i] ? col[e0A + e] : nodeA;
      sB4[i] = vB4[i] ? col[e0B + e] : nodeA;
    }
    float aA4[4], aB4[4];
    unsigned hA4[4], hB4[4];
#pragma unroll
    for (int i = 0; i < 4; ++i) {
      aA4[i] = (H == 4) ? asrc[(size_t)sA4[i] * 4 + hd] : asrc[sA4[i]];
      aB4[i] = (H == 4) ? asrc[(size_t)sB4[i] * 4 + hd] : asrc[sB4[i]];
      hA4[i] = *(const unsigned*)(h + (size_t)sA4[i] * 128 + c0);
      hB4[i] = *(const unsigned*)(h + (size_t)sB4[i] * 128 + c0);
    }
#pragma unroll
    for (int i = 0; i < 4; ++i) {
      float ya = aA4[i] + adA; ya = (ya > 0.f) ? ya : NEG_SLOPE * ya;
      float eeA = vA4[i] ? __expf(ya) : 0.f;
      float yb = aB4[i] + adB; yb = (yb > 0.f) ? yb : NEG_SLOPE * yb;
      float eeB = vB4[i] ? __expf(yb) : 0.f;
      accA.x = fmaf(bf2f((unsigned short)(hA4[i] & 0xffffu)), eeA, accA.x);
      accA.y = fmaf(bf2f((unsigned short)(hA4[i] >> 16)), eeA, accA.y);
      accB.x = fmaf(bf2f((unsigned short)(hB4[i] & 0xffffu)), eeB, accB.x);
      accB.y = fmaf(bf2f((unsigned short)(hB4[i] >> 16)), eeB, accB.y);
    }
  }

  float bx = bias[c0], by = bias[c0 + 1];
  accA.x = fmaf(accA.x, invA, bx);
  accA.y = fmaf(accA.y, invA, by);
  accB.x = fmaf(accB.x, invB, bx);
  accB.y = fmaf(accB.y, invB, by);
  if (RELU) {
    accA.x = fmaxf(accA.x, 0.f); accA.y = fmaxf(accA.y, 0.f);
    accB.x = fmaxf(accB.x, 0.f); accB.y = fmaxf(accB.y, 0.f);
  }

  if (!LNOUT) {
    unsigned pa = (unsigned)f2bf(accA.x) | ((unsigned)f2bf(accA.y) << 16);
    *(unsigned*)(outbf + (size_t)nodeA * 128 + c0) = pa;
    if (hasB) {
      unsigned pb = (unsigned)f2bf(accB.x) | ((unsigned)f2bf(accB.y) << 16);
      *(unsigned*)(outbf + (size_t)nodeB * 128 + c0) = pb;
    }
  } else {
    // LayerNorm for A and B (independent shfl chains, interleaved), then
    // coalesced bf16 row writes — no atomics.
    float sA = accA.x + accA.y;
    float sB = accB.x + accB.y;
#pragma unroll
    for (int off = 1; off < 64; off <<= 1) {
      sA += __shfl_xor(sA, off, 64);
      sB += __shfl_xor(sB, off, 64);
    }
    float muA = sA * (1.f / 128.f), muB = sB * (1.f / 128.f);
    float dxA = accA.x - muA, dyA = accA.y - muA;
    float dxB = accB.x - muB, dyB = accB.y - muB;
    float vA = dxA * dxA + dyA * dyA;
    float vB = dxB * dxB + dyB * dyB;
#pragma unroll
    for (int off = 1; off < 64; off <<= 1) {
      vA += __shfl_xor(vA, off, 64);
      vB += __shfl_xor(vB, off, 64);
    }
    float ivA = rsqrtf(vA * (1.f / 128.f) + LN_EPS);
    float ivB = rsqrtf(vB * (1.f / 128.f) + LN_EPS);
    float gx = gamma[c0], gy = gamma[c0 + 1];
    float ex = beta[c0], ey = beta[c0 + 1];
    float oxA = fmaf(dxA * ivA, gx, ex), oyA = fmaf(dyA * ivA, gy, ey);
    unsigned pa = (unsigned)f2bf(oxA) | ((unsigned)f2bf(oyA) << 16);
    *(unsigned*)(outbf + (size_t)nodeA * 128 + c0) = pa;
    if (hasB) {
      float oxB = fmaf(dxB * ivB, gx, ex), oyB = fmaf(dyB * ivB, gy, ey);
      unsigned pb = (unsigned)f2bf(oxB) | ((unsigned)f2bf(oyB) << 16);
      *(unsigned*)(outbf + (size_t)nodeB * 128 + c0) = pb;
    }
  }
}

// ---------------- mean pool: one wave per graph, contiguous rows -------------

__global__ __launch_bounds__(256) void pool_kernel(const unsigned short* __restrict__ hln,
                                                   const int* __restrict__ gp,
                                                   float* __restrict__ out, int G) {
  int g = (blockIdx.x * 256 + threadIdx.x) >> 6;
  int lane = threadIdx.x & 63;
  if (g >= G) return;
  int s = gp[g], e = gp[g + 1];
  float ax = 0.f, ay = 0.f;
#pragma unroll 1
  for (int i = s; i < e; ++i) {
    unsigned v = *(const unsigned*)(hln + (size_t)i * 128 + lane * 2);
    ax += bf2f((unsigned short)(v & 0xffffu));
    ay += bf2f((unsigned short)(v >> 16));
  }
  int c = e - s;
  float sc = 1.f / (float)((c > 0) ? c : 1);
  *(float2*)(out + (size_t)g * 128 + lane * 2) = make_float2(ax * sc, ay * sc);
}

// ---------------- launch ----------------

extern "C" void kernel_launch(void* const* d_in, const int* in_sizes, int n_in,
                              void* d_out, int out_size, void* d_ws, size_t ws_size,
                              hipStream_t stream) {
  const float* x = (const float*)d_in[0];
  const int* ei = (const int*)d_in[1];
  const int* batch = (const int*)d_in[2];
  const float* W1 = (const float*)d_in[3];
  const float* att_src1 = (const float*)d_in[4];
  const float* att_dst1 = (const float*)d_in[5];
  const float* b1 = (const float*)d_in[6];
  const float* W2 = (const float*)d_in[7];
  const float* att_src2 = (const float*)d_in[8];
  const float* att_dst2 = (const float*)d_in[9];
  const float* b2 = (const float*)d_in[10];
  const float* gamma = (const float*)d_in[11];
  const float* beta = (const float*)d_in[12];
  float* out = (float*)d_out;

  const int N = N_NODES_C, E = N_EDGES_C, G = NUM_GRAPHS_C;
  const int* src = ei;
  const int* dst = ei + E;

  float* p = (float*)d_ws;
  float* asrc1 = p; p += (size_t)N * 4;
  float* adst1 = p; p += (size_t)N * 4;
  float* asrc2 = p; p += N;
  float* adst2 = p; p += N;
  float* den1 = p;  p += (size_t)N * 4;
  float* den2 = p;  p += N;
  int* ip = (int*)p;
  int* deg = ip;       ip += N;
  int* cursor = ip;    ip += N;
  int* col = ip;       ip += E;
  int* bsums = ip;     ip += 256;
  int* bsums2 = ip;    ip += 256;
  int* row_ptr = ip;   ip += N + 2;   // +pad to keep 8B alignment downstream
  int* graph_ptr = ip; ip += G + 2;
  unsigned short* h1bf = (unsigned short*)ip;          // [N*128] bf16; reused as LN'd rows
  unsigned short* hbbf = h1bf + (size_t)N * 128;       // [N*128] bf16
  unsigned short* h2bf = hbbf + (size_t)N * 128;       // [N*128] bf16
  (void)ws_size; (void)in_sizes; (void)n_in; (void)out_size;

  hipMemsetAsync(deg, 0, sizeof(int) * (size_t)N, stream);
  hipMemsetAsync(cursor, 0, sizeof(int) * (size_t)N, stream);
  hipMemsetAsync(den1, 0, sizeof(float) * (size_t)N * 4, stream);
  hipMemsetAsync(den2, 0, sizeof(float) * (size_t)N, stream);

  // CSR by destination + graph ranges from sorted batch
  count_deg_kernel<<<(E + 255) / 256, 256, 0, stream>>>(dst, deg, E);
  int nblk = (N + 1023) / 1024;
  scan_kernel<<<nblk, 256, 0, stream>>>(deg, row_ptr, bsums, N);
  scan_kernel<<<1, 256, 0, stream>>>(bsums, bsums2, nullptr, nblk);
  scan_addoff_kernel<<<nblk, 256, 0, stream>>>(row_ptr, bsums2, N, E);
  fill_csr_kernel<<<(E + 255) / 256, 256, 0, stream>>>(src, dst, row_ptr, cursor, col, E);
  graph_ptr_kernel<<<(N + 1 + 255) / 256, 256, 0, stream>>>(batch, graph_ptr, N, G);

  int pairs = (N + 1) / 2;
  int pblocks = (int)(((size_t)pairs * 64 + 255) / 256);  // 2 nodes per wave
  int eblocks = (E + 255) / 256;

  // Layer 1: GAT(128 -> 4x32), ReLU
  gemm_att<4, false><<<(N + 31) / 32, 256, 0, stream>>>(
      x, W1, att_src1, att_dst1, h1bf, asrc1, adst1, N);
  edge_denom_kernel<4><<<eblocks, 256, 0, stream>>>(src, dst, asrc1, adst1, den1, E);
  gat_agg3_kernel<4, true, false><<<pblocks, 256, 0, stream>>>(
      h1bf, asrc1, adst1, den1, row_ptr, col, b1, nullptr, nullptr, hbbf, N);

  // Layer 2: GAT(128 -> 1x128) + fused LayerNorm -> bf16 rows (no atomics)
  gemm_att<1, true><<<(N + 31) / 32, 256, 0, stream>>>(
      hbbf, W2, att_src2, att_dst2, h2bf, asrc2, adst2, N);
  edge_denom_kernel<1><<<eblocks, 256, 0, stream>>>(src, dst, asrc2, adst2, den2, E);
  gat_agg3_kernel<1, false, true><<<pblocks, 256, 0, stream>>>(
      h2bf, asrc2, adst2, den2, row_ptr, col, b2, gamma, beta, h1bf, N);

  // mean pool per graph: contiguous segmented reduction, writes d_out directly
  pool_kernel<<<(int)(((size_t)G * 64 + 255) / 256), 256, 0, stream>>>(
      h1bf, graph_ptr, out, G);
}

// Round 12
// 417.205 us; speedup vs baseline: 1.8112x; 1.3850x over previous
//
#include <hip/hip_runtime.h>
#include <cstdint>
#include <cstddef>

#define N_NODES_C 200000
#define N_EDGES_C 600000
#define NUM_GRAPHS_C 20000

constexpr float NEG_SLOPE = 0.2f;
constexpr float LN_EPS = 1e-5f;

// bf16 helpers (RNE)
static __device__ __forceinline__ unsigned short f2bf(float f) {
  unsigned u = __float_as_uint(f);
  u = (u + 0x7fffu + ((u >> 16) & 1u)) >> 16;
  return (unsigned short)u;
}
static __device__ __forceinline__ float bf2f(unsigned short s) {
  return __uint_as_float(((unsigned)s) << 16);
}

// ---------------- CSR build ----------------

__global__ __launch_bounds__(256) void count_deg_kernel(const int* __restrict__ dst,
                                                        int* __restrict__ deg, int E) {
  int e = blockIdx.x * 256 + threadIdx.x;
  if (e < E) atomicAdd(&deg[dst[e]], 1);
}

// exclusive scan, 1024 elements per block (256 threads x 4)
__global__ __launch_bounds__(256) void scan_kernel(const int* __restrict__ in,
                                                   int* __restrict__ out,
                                                   int* __restrict__ bsums, int n) {
  __shared__ int ss[256];
  int t = threadIdx.x;
  int base = blockIdx.x * 1024 + t * 4;
  int v[4];
  int s = 0;
#pragma unroll
  for (int j = 0; j < 4; ++j) {
    v[j] = (base + j < n) ? in[base + j] : 0;
    s += v[j];
  }
  ss[t] = s;
  __syncthreads();
  for (int off = 1; off < 256; off <<= 1) {
    int x = (t >= off) ? ss[t - off] : 0;
    __syncthreads();
    ss[t] += x;
    __syncthreads();
  }
  int incl = ss[t];
  int excl = incl - s;
  if (bsums != nullptr && t == 255) bsums[blockIdx.x] = incl;
  int run = excl;
#pragma unroll
  for (int j = 0; j < 4; ++j) {
    if (base + j < n) out[base + j] = run;
    run += v[j];
  }
}

__global__ __launch_bounds__(256) void scan_addoff_kernel(int* __restrict__ data,
                                                          const int* __restrict__ boff,
                                                          int n, int total) {
  int base = blockIdx.x * 1024 + threadIdx.x * 4;
  int add = boff[blockIdx.x];
#pragma unroll
  for (int j = 0; j < 4; ++j) {
    if (base + j < n) data[base + j] += add;
  }
  if (blockIdx.x == 0 && threadIdx.x == 0) data[n] = total;
}

__global__ __launch_bounds__(256) void fill_csr_kernel(const int* __restrict__ src,
                                                       const int* __restrict__ dst,
                                                       const int* __restrict__ row_ptr,
                                                       int* __restrict__ cursor,
                                                       int* __restrict__ col, int E) {
  int e = blockIdx.x * 256 + threadIdx.x;
  if (e < E) {
    int d = dst[e];
    int p = atomicAdd(&cursor[d], 1);
    col[row_ptr[d] + p] = src[e];
  }
}

// ---------------- graph_ptr from sorted batch (boundary detect) ----------------

__global__ __launch_bounds__(256) void graph_ptr_kernel(const int* __restrict__ batch,
                                                        int* __restrict__ gp, int n,
                                                        int G) {
  int i = blockIdx.x * 256 + threadIdx.x;
  if (i < n) {
    int prev = (i == 0) ? -1 : batch[i - 1];
    int cur = batch[i];
#pragma unroll 1
    for (int g = prev + 1; g <= cur; ++g) gp[g] = i;
  } else if (i == n) {
    int last = batch[n - 1];
#pragma unroll 1
    for (int g = last + 1; g <= G; ++g) gp[g] = n;
  }
}

// ---------------- GEMM + att-score epilogue ----------------
// C[M,128] = A[M,128] @ W[128,128]; C written as bf16 (gather/table dtype);
// asrc/adst computed fp32 from the fp32 accumulators. A is fp32 (layer 1)
// or bf16 (layer 2, converted to fp32 while staging into LDS).

template <int H, bool A_BF16>
__global__ __launch_bounds__(256) void gemm_att(const void* __restrict__ Av,
                                                const float* __restrict__ W,
                                                const float* __restrict__ att_src,
                                                const float* __restrict__ att_dst,
                                                unsigned short* __restrict__ Cbf,
                                                float* __restrict__ asrc,
                                                float* __restrict__ adst, int M) {
  __shared__ float As[32][32];
  __shared__ float Ws[32][128];
  int tid = threadIdx.x;
  int tx = tid & 31;   // col group (4 cols)
  int ty = tid >> 5;   // 0..7
  int row0 = blockIdx.x * 32;
  float4 acc[4];
#pragma unroll
  for (int r = 0; r < 4; ++r) acc[r] = make_float4(0.f, 0.f, 0.f, 0.f);

#pragma unroll 1
  for (int k0 = 0; k0 < 128; k0 += 32) {
    {
      int r = tid >> 3;
      int c4 = tid & 7;
      int gr = row0 + r;
      if constexpr (A_BF16) {
        const unsigned short* A = (const unsigned short*)Av;
        ushort4 v = make_ushort4(0, 0, 0, 0);
        if (gr < M) v = *(const ushort4*)(A + (size_t)gr * 128 + k0 + c4 * 4);
        As[r][c4 * 4 + 0] = bf2f(v.x);
        As[r][c4 * 4 + 1] = bf2f(v.y);
        As[r][c4 * 4 + 2] = bf2f(v.z);
        As[r][c4 * 4 + 3] = bf2f(v.w);
      } else {
        const float* A = (const float*)Av;
        float4 v = make_float4(0.f, 0.f, 0.f, 0.f);
        if (gr < M) v = *(const float4*)(A + (size_t)gr * 128 + k0 + c4 * 4);
        *(float4*)&As[r][c4 * 4] = v;
      }
    }
#pragma unroll
    for (int i = 0; i < 4; ++i) {
      int idx = tid + i * 256;
      int r = idx >> 5;
      int c4 = idx & 31;
      *(float4*)&Ws[r][c4 * 4] = *(const float4*)(W + (size_t)(k0 + r) * 128 + c4 * 4);
    }
    __syncthreads();
#pragma unroll
    for (int kk = 0; kk < 32; ++kk) {
      float4 w = *(const float4*)&Ws[kk][tx * 4];
#pragma unroll
      for (int r = 0; r < 4; ++r) {
        float a = As[ty + r * 8][kk];
        acc[r].x = fmaf(a, w.x, acc[r].x);
        acc[r].y = fmaf(a, w.y, acc[r].y);
        acc[r].z = fmaf(a, w.z, acc[r].z);
        acc[r].w = fmaf(a, w.w, acc[r].w);
      }
    }
    __syncthreads();
  }

  float4 vs = *(const float4*)(att_src + tx * 4);
  float4 vd = *(const float4*)(att_dst + tx * 4);
  constexpr int GRP = 32 / H;  // lanes per head within the 32-col group
#pragma unroll
  for (int r = 0; r < 4; ++r) {
    int gr = row0 + ty + r * 8;
    if (gr < M) {
      ushort4 cs;
      cs.x = f2bf(acc[r].x);
      cs.y = f2bf(acc[r].y);
      cs.z = f2bf(acc[r].z);
      cs.w = f2bf(acc[r].w);
      *(ushort4*)(Cbf + (size_t)gr * 128 + tx * 4) = cs;
    }
    float ps = acc[r].x * vs.x + acc[r].y * vs.y + acc[r].z * vs.z + acc[r].w * vs.w;
    float pd = acc[r].x * vd.x + acc[r].y * vd.y + acc[r].z * vd.z + acc[r].w * vd.w;
#pragma unroll
    for (int off = 1; off < GRP; off <<= 1) {
      ps += __shfl_xor(ps, off, 64);
      pd += __shfl_xor(pd, off, 64);
    }
    if ((tx & (GRP - 1)) == 0 && gr < M) {
      int hd = tx / GRP;
      asrc[(size_t)gr * H + hd] = ps;
      adst[(size_t)gr * H + hd] = pd;
    }
  }
}

// ---------------- Pass B: TWO nodes per wave, bf16 gather + inline denom ----
// Each lane walks ALL edges of its node and recomputes ee = exp(leaky(...))
// per edge, so the softmax denominator is just selfe + sum(ee) accumulated
// per-lane in-loop — no atomics, no extra pass, no cross-lane ops (the
// round-11 top-2 dispatches, 2x128us of edge_denom atomics, are deleted).

template <int H, bool RELU, bool LNOUT>
__global__ __launch_bounds__(256) void gat_agg3_kernel(
    const unsigned short* __restrict__ h, const float* __restrict__ asrc,
    const float* __restrict__ adst, const int* __restrict__ row_ptr,
    const int* __restrict__ col, const float* __restrict__ bias,
    const float* __restrict__ gamma, const float* __restrict__ beta,
    unsigned short* __restrict__ outbf, int n) {
  int wid = (blockIdx.x * 256 + threadIdx.x) >> 6;
  int lane = threadIdx.x & 63;
  int nodeA = wid * 2;
  int nodeB = nodeA + 1;
  if (nodeA >= n) return;
  bool hasB = nodeB < n;

  int e0A = row_ptr[nodeA];
  int e1A = row_ptr[nodeA + 1];
  int e1B = hasB ? row_ptr[nodeB + 1] : e1A;
  int e0B = e1A;  // CSR rows are contiguous
  int nedA = e1A - e0A;
  int nedB = e1B - e0B;

  int c0 = lane * 2;
  const int hd = (H == 1) ? 0 : (lane >> 4);

  float adA = (H == 4) ? adst[(size_t)nodeA * 4 + hd] : adst[nodeA];
  float asA = (H == 4) ? asrc[(size_t)nodeA * 4 + hd] : asrc[nodeA];
  int nB = hasB ? nodeB : nodeA;
  float adB = (H == 4) ? adst[(size_t)nB * 4 + hd] : adst[nB];
  float asB = (H == 4) ? asrc[(size_t)nB * 4 + hd] : asrc[nB];

  float xA = asA + adA; xA = (xA > 0.f) ? xA : NEG_SLOPE * xA;
  float selfeA = __expf(xA);
  float xB = asB + adB; xB = (xB > 0.f) ? xB : NEG_SLOPE * xB;
  float selfeB = __expf(xB);

  float denA = selfeA;
  float denB = selfeB;

  float2 accA, accB;
  {
    unsigned ha = *(const unsigned*)(h + (size_t)nodeA * 128 + c0);
    unsigned hb = *(const unsigned*)(h + (size_t)nB * 128 + c0);
    accA.x = bf2f((unsigned short)(ha & 0xffffu)) * selfeA;
    accA.y = bf2f((unsigned short)(ha >> 16)) * selfeA;
    accB.x = bf2f((unsigned short)(hb & 0xffffu)) * selfeB;
    accB.y = bf2f((unsigned short)(hb >> 16)) * selfeB;
  }

  int tmax = (nedA > nedB) ? nedA : nedB;
#pragma unroll 1
  for (int t = 0; t < tmax; t += 4) {
    int sA4[4], sB4[4];
    bool vA4[4], vB4[4];
#pragma unroll
    for (int i = 0; i < 4; ++i) {
      int e = t + i;
      vA4[i] = e < nedA;
      vB4[i] = hasB && e < nedB;
      sA4[i] = vA4[i] ? col[e0A + e] : nodeA;
      sB4[i] = vB4[i] ? col[e0B + e] : nodeA;
    }
    float aA4[4], aB4[4];
    unsigned hA4[4], hB4[4];
#pragma unroll
    for (int i = 0; i < 4; ++i) {
      aA4[i] = (H == 4) ? asrc[(size_t)sA4[i] * 4 + hd] : asrc[sA4[i]];
      aB4[i] = (H == 4) ? asrc[(size_t)sB4[i] * 4 + hd] : asrc[sB4[i]];
      hA4[i] = *(const unsigned*)(h + (size_t)sA4[i] * 128 + c0);
      hB4[i] = *(const unsigned*)(h + (size_t)sB4[i] * 128 + c0);
    }
#pragma unroll
    for (int i = 0; i < 4; ++i) {
      float ya = aA4[i] + adA; ya = (ya > 0.f) ? ya : NEG_SLOPE * ya;
      float eeA = vA4[i] ? __expf(ya) : 0.f;
      float yb = aB4[i] + adB; yb = (yb > 0.f) ? yb : NEG_SLOPE * yb;
      float eeB = vB4[i] ? __expf(yb) : 0.f;
      denA += eeA;
      denB += eeB;
      accA.x = fmaf(bf2f((unsigned short)(hA4[i] & 0xffffu)), eeA, accA.x);
      accA.y = fmaf(bf2f((unsigned short)(hA4[i] >> 16)), eeA, accA.y);
      accB.x = fmaf(bf2f((unsigned short)(hB4[i] & 0xffffu)), eeB, accB.x);
      accB.y = fmaf(bf2f((unsigned short)(hB4[i] >> 16)), eeB, accB.y);
    }
  }

  float invA = 1.f / denA;
  float invB = 1.f / denB;

  float bx = bias[c0], by = bias[c0 + 1];
  accA.x = fmaf(accA.x, invA, bx);
  accA.y = fmaf(accA.y, invA, by);
  accB.x = fmaf(accB.x, invB, bx);
  accB.y = fmaf(accB.y, invB, by);
  if (RELU) {
    accA.x = fmaxf(accA.x, 0.f); accA.y = fmaxf(accA.y, 0.f);
    accB.x = fmaxf(accB.x, 0.f); accB.y = fmaxf(accB.y, 0.f);
  }

  if (!LNOUT) {
    unsigned pa = (unsigned)f2bf(accA.x) | ((unsigned)f2bf(accA.y) << 16);
    *(unsigned*)(outbf + (size_t)nodeA * 128 + c0) = pa;
    if (hasB) {
      unsigned pb = (unsigned)f2bf(accB.x) | ((unsigned)f2bf(accB.y) << 16);
      *(unsigned*)(outbf + (size_t)nodeB * 128 + c0) = pb;
    }
  } else {
    // LayerNorm for A and B (independent shfl chains, interleaved), then
    // coalesced bf16 row writes — no atomics.
    float sA = accA.x + accA.y;
    float sB = accB.x + accB.y;
#pragma unroll
    for (int off = 1; off < 64; off <<= 1) {
      sA += __shfl_xor(sA, off, 64);
      sB += __shfl_xor(sB, off, 64);
    }
    float muA = sA * (1.f / 128.f), muB = sB * (1.f / 128.f);
    float dxA = accA.x - muA, dyA = accA.y - muA;
    float dxB = accB.x - muB, dyB = accB.y - muB;
    float vA = dxA * dxA + dyA * dyA;
    float vB = dxB * dxB + dyB * dyB;
#pragma unroll
    for (int off = 1; off < 64; off <<= 1) {
      vA += __shfl_xor(vA, off, 64);
      vB += __shfl_xor(vB, off, 64);
    }
    float ivA = rsqrtf(vA * (1.f / 128.f) + LN_EPS);
    float ivB = rsqrtf(vB * (1.f / 128.f) + LN_EPS);
    float gx = gamma[c0], gy = gamma[c0 + 1];
    float ex = beta[c0], ey = beta[c0 + 1];
    float oxA = fmaf(dxA * ivA, gx, ex), oyA = fmaf(dyA * ivA, gy, ey);
    unsigned pa = (unsigned)f2bf(oxA) | ((unsigned)f2bf(oyA) << 16);
    *(unsigned*)(outbf + (size_t)nodeA * 128 + c0) = pa;
    if (hasB) {
      float oxB = fmaf(dxB * ivB, gx, ex), oyB = fmaf(dyB * ivB, gy, ey);
      unsigned pb = (unsigned)f2bf(oxB) | ((unsigned)f2bf(oyB) << 16);
      *(unsigned*)(outbf + (size_t)nodeB * 128 + c0) = pb;
    }
  }
}

// ---------------- mean pool: one wave per graph, contiguous rows -------------

__global__ __launch_bounds__(256) void pool_kernel(const unsigned short* __restrict__ hln,
                                                   const int* __restrict__ gp,
                                                   float* __restrict__ out, int G) {
  int g = (blockIdx.x * 256 + threadIdx.x) >> 6;
  int lane = threadIdx.x & 63;
  if (g >= G) return;
  int s = gp[g], e = gp[g + 1];
  float ax = 0.f, ay = 0.f;
#pragma unroll 1
  for (int i = s; i < e; ++i) {
    unsigned v = *(const unsigned*)(hln + (size_t)i * 128 + lane * 2);
    ax += bf2f((unsigned short)(v & 0xffffu));
    ay += bf2f((unsigned short)(v >> 16));
  }
  int c = e - s;
  float sc = 1.f / (float)((c > 0) ? c : 1);
  *(float2*)(out + (size_t)g * 128 + lane * 2) = make_float2(ax * sc, ay * sc);
}

// ---------------- launch ----------------

extern "C" void kernel_launch(void* const* d_in, const int* in_sizes, int n_in,
                              void* d_out, int out_size, void* d_ws, size_t ws_size,
                              hipStream_t stream) {
  const float* x = (const float*)d_in[0];
  const int* ei = (const int*)d_in[1];
  const int* batch = (const int*)d_in[2];
  const float* W1 = (const float*)d_in[3];
  const float* att_src1 = (const float*)d_in[4];
  const float* att_dst1 = (const float*)d_in[5];
  const float* b1 = (const float*)d_in[6];
  const float* W2 = (const float*)d_in[7];
  const float* att_src2 = (const float*)d_in[8];
  const float* att_dst2 = (const float*)d_in[9];
  const float* b2 = (const float*)d_in[10];
  const float* gamma = (const float*)d_in[11];
  const float* beta = (const float*)d_in[12];
  float* out = (float*)d_out;

  const int N = N_NODES_C, E = N_EDGES_C, G = NUM_GRAPHS_C;
  const int* src = ei;
  const int* dst = ei + E;

  float* p = (float*)d_ws;
  float* asrc1 = p; p += (size_t)N * 4;
  float* adst1 = p; p += (size_t)N * 4;
  float* asrc2 = p; p += N;
  float* adst2 = p; p += N;
  int* ip = (int*)p;
  int* deg = ip;       ip += N;
  int* cursor = ip;    ip += N;
  int* col = ip;       ip += E;
  int* bsums = ip;     ip += 256;
  int* bsums2 = ip;    ip += 256;
  int* row_ptr = ip;   ip += N + 2;   // +pad to keep 8B alignment downstream
  int* graph_ptr = ip; ip += G + 2;
  unsigned short* h1bf = (unsigned short*)ip;          // [N*128] bf16; reused as LN'd rows
  unsigned short* hbbf = h1bf + (size_t)N * 128;       // [N*128] bf16
  unsigned short* h2bf = hbbf + (size_t)N * 128;       // [N*128] bf16
  (void)ws_size; (void)in_sizes; (void)n_in; (void)out_size;

  hipMemsetAsync(deg, 0, sizeof(int) * (size_t)N, stream);
  hipMemsetAsync(cursor, 0, sizeof(int) * (size_t)N, stream);

  // CSR by destination + graph ranges from sorted batch
  count_deg_kernel<<<(E + 255) / 256, 256, 0, stream>>>(dst, deg, E);
  int nblk = (N + 1023) / 1024;
  scan_kernel<<<nblk, 256, 0, stream>>>(deg, row_ptr, bsums, N);
  scan_kernel<<<1, 256, 0, stream>>>(bsums, bsums2, nullptr, nblk);
  scan_addoff_kernel<<<nblk, 256, 0, stream>>>(row_ptr, bsums2, N, E);
  fill_csr_kernel<<<(E + 255) / 256, 256, 0, stream>>>(src, dst, row_ptr, cursor, col, E);
  graph_ptr_kernel<<<(N + 1 + 255) / 256, 256, 0, stream>>>(batch, graph_ptr, N, G);

  int pairs = (N + 1) / 2;
  int pblocks = (int)(((size_t)pairs * 64 + 255) / 256);  // 2 nodes per wave

  // Layer 1: GAT(128 -> 4x32), ReLU
  gemm_att<4, false><<<(N + 31) / 32, 256, 0, stream>>>(
      x, W1, att_src1, att_dst1, h1bf, asrc1, adst1, N);
  gat_agg3_kernel<4, true, false><<<pblocks, 256, 0, stream>>>(
      h1bf, asrc1, adst1, row_ptr, col, b1, nullptr, nullptr, hbbf, N);

  // Layer 2: GAT(128 -> 1x128) + fused LayerNorm -> bf16 rows (no atomics)
  gemm_att<1, true><<<(N + 31) / 32, 256, 0, stream>>>(
      hbbf, W2, att_src2, att_dst2, h2bf, asrc2, adst2, N);
  gat_agg3_kernel<1, false, true><<<pblocks, 256, 0, stream>>>(
      h2bf, asrc2, adst2, row_ptr, col, b2, gamma, beta, h1bf, N);

  // mean pool per graph: contiguous segmented reduction, writes d_out directly
  pool_kernel<<<(int)(((size_t)G * 64 + 255) / 256), 256, 0, stream>>>(
      h1bf, graph_ptr, out, G);
}

// Round 13
// 297.333 us; speedup vs baseline: 2.5414x; 1.4032x over previous
//
#include <hip/hip_runtime.h>
#include <cstdint>
#include <cstddef>

#define N_NODES_C 200000
#define N_EDGES_C 600000
#define NUM_GRAPHS_C 20000

constexpr float NEG_SLOPE = 0.2f;
constexpr float LN_EPS = 1e-5f;

typedef __attribute__((ext_vector_type(8))) short bf16x8;
typedef __attribute__((ext_vector_type(4))) float f32x4;

// bf16 helpers (RNE)
static __device__ __forceinline__ unsigned short f2bf(float f) {
  unsigned u = __float_as_uint(f);
  u = (u + 0x7fffu + ((u >> 16) & 1u)) >> 16;
  return (unsigned short)u;
}
static __device__ __forceinline__ float bf2f(unsigned short s) {
  return __uint_as_float(((unsigned)s) << 16);
}

// ---------------- CSR build ----------------

__global__ __launch_bounds__(256) void count_deg_kernel(const int* __restrict__ dst,
                                                        int* __restrict__ deg, int E) {
  int e = blockIdx.x * 256 + threadIdx.x;
  if (e < E) atomicAdd(&deg[dst[e]], 1);
}

__global__ __launch_bounds__(256) void scan_kernel(const int* __restrict__ in,
                                                   int* __restrict__ out,
                                                   int* __restrict__ bsums, int n) {
  __shared__ int ss[256];
  int t = threadIdx.x;
  int base = blockIdx.x * 1024 + t * 4;
  int v[4];
  int s = 0;
#pragma unroll
  for (int j = 0; j < 4; ++j) {
    v[j] = (base + j < n) ? in[base + j] : 0;
    s += v[j];
  }
  ss[t] = s;
  __syncthreads();
  for (int off = 1; off < 256; off <<= 1) {
    int x = (t >= off) ? ss[t - off] : 0;
    __syncthreads();
    ss[t] += x;
    __syncthreads();
  }
  int incl = ss[t];
  int excl = incl - s;
  if (bsums != nullptr && t == 255) bsums[blockIdx.x] = incl;
  int run = excl;
#pragma unroll
  for (int j = 0; j < 4; ++j) {
    if (base + j < n) out[base + j] = run;
    run += v[j];
  }
}

__global__ __launch_bounds__(256) void scan_addoff_kernel(int* __restrict__ data,
                                                          const int* __restrict__ boff,
                                                          int n, int total) {
  int base = blockIdx.x * 1024 + threadIdx.x * 4;
  int add = boff[blockIdx.x];
#pragma unroll
  for (int j = 0; j < 4; ++j) {
    if (base + j < n) data[base + j] += add;
  }
  if (blockIdx.x == 0 && threadIdx.x == 0) data[n] = total;
}

__global__ __launch_bounds__(256) void fill_csr_kernel(const int* __restrict__ src,
                                                       const int* __restrict__ dst,
                                                       const int* __restrict__ row_ptr,
                                                       int* __restrict__ cursor,
                                                       int* __restrict__ col, int E) {
  int e = blockIdx.x * 256 + threadIdx.x;
  if (e < E) {
    int d = dst[e];
    int p = atomicAdd(&cursor[d], 1);
    col[row_ptr[d] + p] = src[e];
  }
}

// ---------------- graph_ptr from sorted batch ----------------

__global__ __launch_bounds__(256) void graph_ptr_kernel(const int* __restrict__ batch,
                                                        int* __restrict__ gp, int n,
                                                        int G) {
  int i = blockIdx.x * 256 + threadIdx.x;
  if (i < n) {
    int prev = (i == 0) ? -1 : batch[i - 1];
    int cur = batch[i];
#pragma unroll 1
    for (int g = prev + 1; g <= cur; ++g) gp[g] = i;
  } else if (i == n) {
    int last = batch[n - 1];
#pragma unroll 1
    for (int g = last + 1; g <= G; ++g) gp[g] = n;
  }
}

// ---------------- W prep: fp32 [k][n] -> bf16 W^T padded [n][136] ----------
// Produces the exact LDS image: row n holds W[k][n] for k=0..127 (k contiguous
// per n, so B-frags read 8 consecutive k as one b128), rows padded to 136
// shorts (272 B, 16B-aligned, uniform LDS bank spread for frag reads).

__global__ __launch_bounds__(256) void wprep_kernel(const float* __restrict__ W,
                                                    unsigned short* __restrict__ Wtp) {
  int idx = blockIdx.x * 256 + threadIdx.x;
  if (idx >= 128 * 136) return;
  int n = idx / 136, k = idx % 136;
  Wtp[idx] = (k < 128) ? f2bf(W[(size_t)k * 128 + n]) : (unsigned short)0;
}

// ---------------- MFMA GEMM + att-score epilogue ----------------
// C[M,128] = A[M,128] @ W[128,128] in bf16 MFMA (fp32 accum). Block: 64 rows,
// 4 waves x 16 rows x 8 n-tiles, K=128 = 4 mfma_16x16x32 steps per tile.
// Fragment maps (HW-verified, cdna4 guide §3):
//   A-frag: row = lane&15, k = (lane>>4)*8 + j
//   B-frag: col = lane&15, k = (lane>>4)*8 + j  (needs W^T: k contiguous)
//   C/D:    col = lane&15, row = (lane>>4)*4 + reg   [m89]
// M == 200000 == 64*3125 exactly -> no row guards.

template <int H, bool A_BF16>
__global__ __launch_bounds__(256) void gemm_att_mfma(
    const void* __restrict__ Av, const unsigned short* __restrict__ Wtp,
    const float* __restrict__ att_src, const float* __restrict__ att_dst,
    unsigned short* __restrict__ Cbf, float* __restrict__ asrc,
    float* __restrict__ adst) {
  __shared__ __align__(16) unsigned short Alds[64 * 136];
  __shared__ __align__(16) unsigned short Wlds[128 * 136];
  int tid = threadIdx.x;
  int lane = tid & 63;
  int wave = tid >> 6;
  int row0 = blockIdx.x * 64;

  // stage W^T image: linear copy, 2176 chunks of 8 shorts (conflict-free)
#pragma unroll
  for (int i = 0; i < 9; ++i) {
    int ch = tid + i * 256;
    if (ch < 2176) *(bf16x8*)&Wlds[ch * 8] = *(const bf16x8*)&Wtp[(size_t)ch * 8];
  }
  // stage A rows -> padded [64][136] bf16, 1024 chunks of 8 cols
#pragma unroll
  for (int i = 0; i < 4; ++i) {
    int ch = tid + i * 256;
    int r = ch >> 4, c = ch & 15;
    if constexpr (A_BF16) {
      bf16x8 v = *(const bf16x8*)((const unsigned short*)Av +
                                  (size_t)(row0 + r) * 128 + c * 8);
      *(bf16x8*)&Alds[r * 136 + c * 8] = v;
    } else {
      const float* A = (const float*)Av;
      float4 v0 = *(const float4*)(A + (size_t)(row0 + r) * 128 + c * 8);
      float4 v1 = *(const float4*)(A + (size_t)(row0 + r) * 128 + c * 8 + 4);
      unsigned short tmp[8] = {f2bf(v0.x), f2bf(v0.y), f2bf(v0.z), f2bf(v0.w),
                               f2bf(v1.x), f2bf(v1.y), f2bf(v1.z), f2bf(v1.w)};
      *(bf16x8*)&Alds[r * 136 + c * 8] = *(bf16x8*)tmp;
    }
  }
  __syncthreads();

  int l15 = lane & 15;
  int lg = lane >> 4;
  int wr = wave * 16;

  f32x4 acc[8];
#pragma unroll
  for (int nt = 0; nt < 8; ++nt) acc[nt] = (f32x4){0.f, 0.f, 0.f, 0.f};

#pragma unroll
  for (int ks = 0; ks < 4; ++ks) {
    bf16x8 af = *(const bf16x8*)&Alds[(wr + l15) * 136 + ks * 32 + lg * 8];
#pragma unroll
    for (int nt = 0; nt < 8; ++nt) {
      bf16x8 bfr = *(const bf16x8*)&Wlds[(nt * 16 + l15) * 136 + ks * 32 + lg * 8];
      acc[nt] = __builtin_amdgcn_mfma_f32_16x16x32_bf16(af, bfr, acc[nt], 0, 0, 0);
    }
  }

  // per-lane att-vector values at col nt*16 + l15
  float vsv[8], vdv[8];
#pragma unroll
  for (int nt = 0; nt < 8; ++nt) {
    vsv[nt] = att_src[nt * 16 + l15];
    vdv[nt] = att_dst[nt * 16 + l15];
  }

#pragma unroll
  for (int r = 0; r < 4; ++r) {
    int row = row0 + wr + lg * 4 + r;
    // C write: 8 bf16 stores (16-lane groups cover 32B contiguous segments)
#pragma unroll
    for (int nt = 0; nt < 8; ++nt) {
      Cbf[(size_t)row * 128 + nt * 16 + l15] = f2bf(acc[nt][r]);
    }
    if constexpr (H == 4) {
      float ps[4], pd[4];
#pragma unroll
      for (int hd = 0; hd < 4; ++hd) {
        ps[hd] = acc[2 * hd][r] * vsv[2 * hd] + acc[2 * hd + 1][r] * vsv[2 * hd + 1];
        pd[hd] = acc[2 * hd][r] * vdv[2 * hd] + acc[2 * hd + 1][r] * vdv[2 * hd + 1];
#pragma unroll
        for (int off = 1; off < 16; off <<= 1) {
          ps[hd] += __shfl_xor(ps[hd], off, 64);
          pd[hd] += __shfl_xor(pd[hd], off, 64);
        }
      }
      if (l15 < 4) {
        // static-select (no runtime array index -> no scratch)
        float pss = (l15 == 0) ? ps[0] : (l15 == 1) ? ps[1] : (l15 == 2) ? ps[2] : ps[3];
        float pds = (l15 == 0) ? pd[0] : (l15 == 1) ? pd[1] : (l15 == 2) ? pd[2] : pd[3];
        asrc[(size_t)row * 4 + l15] = pss;
        adst[(size_t)row * 4 + l15] = pds;
      }
    } else {
      float ps = 0.f, pd = 0.f;
#pragma unroll
      for (int nt = 0; nt < 8; ++nt) {
        ps = fmaf(acc[nt][r], vsv[nt], ps);
        pd = fmaf(acc[nt][r], vdv[nt], pd);
      }
#pragma unroll
      for (int off = 1; off < 16; off <<= 1) {
        ps += __shfl_xor(ps, off, 64);
        pd += __shfl_xor(pd, off, 64);
      }
      if (l15 == 0) {
        asrc[row] = ps;
        adst[row] = pd;
      }
    }
  }
}

// ---------------- Pass B: TWO nodes per wave, bf16 gather + inline denom ----

template <int H, bool RELU, bool LNOUT>
__global__ __launch_bounds__(256) void gat_agg3_kernel(
    const unsigned short* __restrict__ h, const float* __restrict__ asrc,
    const float* __restrict__ adst, const int* __restrict__ row_ptr,
    const int* __restrict__ col, const float* __restrict__ bias,
    const float* __restrict__ gamma, const float* __restrict__ beta,
    unsigned short* __restrict__ outbf, int n) {
  int wid = (blockIdx.x * 256 + threadIdx.x) >> 6;
  int lane = threadIdx.x & 63;
  int nodeA = wid * 2;
  int nodeB = nodeA + 1;
  if (nodeA >= n) return;
  bool hasB = nodeB < n;

  int e0A = row_ptr[nodeA];
  int e1A = row_ptr[nodeA + 1];
  int e1B = hasB ? row_ptr[nodeB + 1] : e1A;
  int e0B = e1A;
  int nedA = e1A - e0A;
  int nedB = e1B - e0B;

  int c0 = lane * 2;
  const int hd = (H == 1) ? 0 : (lane >> 4);

  float adA = (H == 4) ? adst[(size_t)nodeA * 4 + hd] : adst[nodeA];
  float asA = (H == 4) ? asrc[(size_t)nodeA * 4 + hd] : asrc[nodeA];
  int nB = hasB ? nodeB : nodeA;
  float adB = (H == 4) ? adst[(size_t)nB * 4 + hd] : adst[nB];
  float asB = (H == 4) ? asrc[(size_t)nB * 4 + hd] : asrc[nB];

  float xA = asA + adA; xA = (xA > 0.f) ? xA : NEG_SLOPE * xA;
  float selfeA = __expf(xA);
  float xB = asB + adB; xB = (xB > 0.f) ? xB : NEG_SLOPE * xB;
  float selfeB = __expf(xB);

  float denA = selfeA;
  float denB = selfeB;

  float2 accA, accB;
  {
    unsigned ha = *(const unsigned*)(h + (size_t)nodeA * 128 + c0);
    unsigned hb = *(const unsigned*)(h + (size_t)nB * 128 + c0);
    accA.x = bf2f((unsigned short)(ha & 0xffffu)) * selfeA;
    accA.y = bf2f((unsigned short)(ha >> 16)) * selfeA;
    accB.x = bf2f((unsigned short)(hb & 0xffffu)) * selfeB;
    accB.y = bf2f((unsigned short)(hb >> 16)) * selfeB;
  }

  int tmax = (nedA > nedB) ? nedA : nedB;
#pragma unroll 1
  for (int t = 0; t < tmax; t += 4) {
    int sA4[4], sB4[4];
    bool vA4[4], vB4[4];
#pragma unroll
    for (int i = 0; i < 4; ++i) {
      int e = t + i;
      vA4[i] = e < nedA;
      vB4[i] = hasB && e < nedB;
      sA4[i] = vA4[i] ? col[e0A + e] : nodeA;
      sB4[i] = vB4[i] ? col[e0B + e] : nodeA;
    }
    float aA4[4], aB4[4];
    unsigned hA4[4], hB4[4];
#pragma unroll
    for (int i = 0; i < 4; ++i) {
      aA4[i] = (H == 4) ? asrc[(size_t)sA4[i] * 4 + hd] : asrc[sA4[i]];
      aB4[i] = (H == 4) ? asrc[(size_t)sB4[i] * 4 + hd] : asrc[sB4[i]];
      hA4[i] = *(const unsigned*)(h + (size_t)sA4[i] * 128 + c0);
      hB4[i] = *(const unsigned*)(h + (size_t)sB4[i] * 128 + c0);
    }
#pragma unroll
    for (int i = 0; i < 4; ++i) {
      float ya = aA4[i] + adA; ya = (ya > 0.f) ? ya : NEG_SLOPE * ya;
      float eeA = vA4[i] ? __expf(ya) : 0.f;
      float yb = aB4[i] + adB; yb = (yb > 0.f) ? yb : NEG_SLOPE * yb;
      float eeB = vB4[i] ? __expf(yb) : 0.f;
      denA += eeA;
      denB += eeB;
      accA.x = fmaf(bf2f((unsigned short)(hA4[i] & 0xffffu)), eeA, accA.x);
      accA.y = fmaf(bf2f((unsigned short)(hA4[i] >> 16)), eeA, accA.y);
      accB.x = fmaf(bf2f((unsigned short)(hB4[i] & 0xffffu)), eeB, accB.x);
      accB.y = fmaf(bf2f((unsigned short)(hB4[i] >> 16)), eeB, accB.y);
    }
  }

  float invA = 1.f / denA;
  float invB = 1.f / denB;

  float bx = bias[c0], by = bias[c0 + 1];
  accA.x = fmaf(accA.x, invA, bx);
  accA.y = fmaf(accA.y, invA, by);
  accB.x = fmaf(accB.x, invB, bx);
  accB.y = fmaf(accB.y, invB, by);
  if (RELU) {
    accA.x = fmaxf(accA.x, 0.f); accA.y = fmaxf(accA.y, 0.f);
    accB.x = fmaxf(accB.x, 0.f); accB.y = fmaxf(accB.y, 0.f);
  }

  if (!LNOUT) {
    unsigned pa = (unsigned)f2bf(accA.x) | ((unsigned)f2bf(accA.y) << 16);
    *(unsigned*)(outbf + (size_t)nodeA * 128 + c0) = pa;
    if (hasB) {
      unsigned pb = (unsigned)f2bf(accB.x) | ((unsigned)f2bf(accB.y) << 16);
      *(unsigned*)(outbf + (size_t)nodeB * 128 + c0) = pb;
    }
  } else {
    float sA = accA.x + accA.y;
    float sB = accB.x + accB.y;
#pragma unroll
    for (int off = 1; off < 64; off <<= 1) {
      sA += __shfl_xor(sA, off, 64);
      sB += __shfl_xor(sB, off, 64);
    }
    float muA = sA * (1.f / 128.f), muB = sB * (1.f / 128.f);
    float dxA = accA.x - muA, dyA = accA.y - muA;
    float dxB = accB.x - muB, dyB = accB.y - muB;
    float vA = dxA * dxA + dyA * dyA;
    float vB = dxB * dxB + dyB * dyB;
#pragma unroll
    for (int off = 1; off < 64; off <<= 1) {
      vA += __shfl_xor(vA, off, 64);
      vB += __shfl_xor(vB, off, 64);
    }
    float ivA = rsqrtf(vA * (1.f / 128.f) + LN_EPS);
    float ivB = rsqrtf(vB * (1.f / 128.f) + LN_EPS);
    float gx = gamma[c0], gy = gamma[c0 + 1];
    float ex = beta[c0], ey = beta[c0 + 1];
    float oxA = fmaf(dxA * ivA, gx, ex), oyA = fmaf(dyA * ivA, gy, ey);
    unsigned pa = (unsigned)f2bf(oxA) | ((unsigned)f2bf(oyA) << 16);
    *(unsigned*)(outbf + (size_t)nodeA * 128 + c0) = pa;
    if (hasB) {
      float oxB = fmaf(dxB * ivB, gx, ex), oyB = fmaf(dyB * ivB, gy, ey);
      unsigned pb = (unsigned)f2bf(oxB) | ((unsigned)f2bf(oyB) << 16);
      *(unsigned*)(outbf + (size_t)nodeB * 128 + c0) = pb;
    }
  }
}

// ---------------- mean pool: one wave per graph, contiguous rows -------------

__global__ __launch_bounds__(256) void pool_kernel(const unsigned short* __restrict__ hln,
                                                   const int* __restrict__ gp,
                                                   float* __restrict__ out, int G) {
  int g = (blockIdx.x * 256 + threadIdx.x) >> 6;
  int lane = threadIdx.x & 63;
  if (g >= G) return;
  int s = gp[g], e = gp[g + 1];
  float ax = 0.f, ay = 0.f;
#pragma unroll 1
  for (int i = s; i < e; ++i) {
    unsigned v = *(const unsigned*)(hln + (size_t)i * 128 + lane * 2);
    ax += bf2f((unsigned short)(v & 0xffffu));
    ay += bf2f((unsigned short)(v >> 16));
  }
  int c = e - s;
  float sc = 1.f / (float)((c > 0) ? c : 1);
  *(float2*)(out + (size_t)g * 128 + lane * 2) = make_float2(ax * sc, ay * sc);
}

// ---------------- launch ----------------

extern "C" void kernel_launch(void* const* d_in, const int* in_sizes, int n_in,
                              void* d_out, int out_size, void* d_ws, size_t ws_size,
                              hipStream_t stream) {
  const float* x = (const float*)d_in[0];
  const int* ei = (const int*)d_in[1];
  const int* batch = (const int*)d_in[2];
  const float* W1 = (const float*)d_in[3];
  const float* att_src1 = (const float*)d_in[4];
  const float* att_dst1 = (const float*)d_in[5];
  const float* b1 = (const float*)d_in[6];
  const float* W2 = (const float*)d_in[7];
  const float* att_src2 = (const float*)d_in[8];
  const float* att_dst2 = (const float*)d_in[9];
  const float* b2 = (const float*)d_in[10];
  const float* gamma = (const float*)d_in[11];
  const float* beta = (const float*)d_in[12];
  float* out = (float*)d_out;

  const int N = N_NODES_C, E = N_EDGES_C, G = NUM_GRAPHS_C;
  const int* src = ei;
  const int* dst = ei + E;

  float* p = (float*)d_ws;
  float* asrc1 = p; p += (size_t)N * 4;
  float* adst1 = p; p += (size_t)N * 4;
  float* asrc2 = p; p += N;
  float* adst2 = p; p += N;
  int* ip = (int*)p;
  int* deg = ip;       ip += N;
  int* cursor = ip;    ip += N;
  int* col = ip;       ip += E;
  int* bsums = ip;     ip += 256;
  int* bsums2 = ip;    ip += 256;
  int* row_ptr = ip;   ip += N + 2;
  int* graph_ptr = ip; ip += G + 2;
  unsigned short* h1bf = (unsigned short*)ip;          // [N*128] bf16; reused as LN'd rows
  unsigned short* hbbf = h1bf + (size_t)N * 128;
  unsigned short* h2bf = hbbf + (size_t)N * 128;
  unsigned short* wt1 = h2bf + (size_t)N * 128;        // [128*136] bf16 W^T padded
  unsigned short* wt2 = wt1 + 128 * 136;
  (void)ws_size; (void)in_sizes; (void)n_in; (void)out_size;

  hipMemsetAsync(deg, 0, sizeof(int) * (size_t)N, stream);
  hipMemsetAsync(cursor, 0, sizeof(int) * (size_t)N, stream);

  // CSR by destination + graph ranges + weight prep
  count_deg_kernel<<<(E + 255) / 256, 256, 0, stream>>>(dst, deg, E);
  int nblk = (N + 1023) / 1024;
  scan_kernel<<<nblk, 256, 0, stream>>>(deg, row_ptr, bsums, N);
  scan_kernel<<<1, 256, 0, stream>>>(bsums, bsums2, nullptr, nblk);
  scan_addoff_kernel<<<nblk, 256, 0, stream>>>(row_ptr, bsums2, N, E);
  fill_csr_kernel<<<(E + 255) / 256, 256, 0, stream>>>(src, dst, row_ptr, cursor, col, E);
  graph_ptr_kernel<<<(N + 1 + 255) / 256, 256, 0, stream>>>(batch, graph_ptr, N, G);
  wprep_kernel<<<(128 * 136 + 255) / 256, 256, 0, stream>>>(W1, wt1);
  wprep_kernel<<<(128 * 136 + 255) / 256, 256, 0, stream>>>(W2, wt2);

  int pairs = (N + 1) / 2;
  int pblocks = (int)(((size_t)pairs * 64 + 255) / 256);  // 2 nodes per wave
  int gblocks = N / 64;  // 200000 = 64*3125 exactly

  // Layer 1: GAT(128 -> 4x32), ReLU
  gemm_att_mfma<4, false><<<gblocks, 256, 0, stream>>>(
      x, wt1, att_src1, att_dst1, h1bf, asrc1, adst1);
  gat_agg3_kernel<4, true, false><<<pblocks, 256, 0, stream>>>(
      h1bf, asrc1, adst1, row_ptr, col, b1, nullptr, nullptr, hbbf, N);

  // Layer 2: GAT(128 -> 1x128) + fused LayerNorm -> bf16 rows
  gemm_att_mfma<1, true><<<gblocks, 256, 0, stream>>>(
      hbbf, wt2, att_src2, att_dst2, h2bf, asrc2, adst2);
  gat_agg3_kernel<1, false, true><<<pblocks, 256, 0, stream>>>(
      h2bf, asrc2, adst2, row_ptr, col, b2, gamma, beta, h1bf, N);

  // mean pool per graph: contiguous segmented reduction -> d_out
  pool_kernel<<<(int)(((size_t)G * 64 + 255) / 256), 256, 0, stream>>>(
      h1bf, graph_ptr, out, G);
}